// Round 10
// baseline (263.839 us; speedup 1.0000x reference)
//
#include <hip/hip_runtime.h>
#include <math.h>

#define N_NODES 32768
#define N_EDGES 524288
#define DIM     128

static constexpr size_t NM = (size_t)N_NODES * DIM;   // 4194304

typedef __attribute__((ext_vector_type(8)))  short bf8;     // 8 bf16
typedef __attribute__((ext_vector_type(4)))  float f32x4;
typedef __attribute__((ext_vector_type(16))) float f32x16;

__device__ __forceinline__ short f2bs(float x) {
    union { float f; unsigned int u; } v; v.f = x;
    unsigned int r = v.u + 0x7fffu + ((v.u >> 16) & 1u);
    return (short)(r >> 16);
}
__device__ __forceinline__ unsigned int pk2(float a, float b) {
    return (unsigned int)(unsigned short)f2bs(a) |
           ((unsigned int)(unsigned short)f2bs(b) << 16);
}
__device__ __forceinline__ float2 bs2f(unsigned int u) {
    union { unsigned int a; float f; } lo, hi;
    lo.a = u << 16; hi.a = u & 0xffff0000u;
    float2 r; r.x = lo.f; r.y = hi.f; return r;
}
__device__ __forceinline__ float bs1f(short s) {
    union { unsigned int a; float f; } t;
    t.a = ((unsigned int)(unsigned short)s) << 16; return t.f;
}

// ---------------------------------------------------------------------------
// k1: cvt + zero-deg (R6-proven). x->bf16, weights->wbf, biases->bcat, deg=0.
// wbf short-offsets: Wres 0, Wk 16384, Wq 32768, Wv 49152, Wskip 65536,
//                    Win 81920, Wout 131072, W1 147456, W2 180224 (end 212992)
// ---------------------------------------------------------------------------
__global__ __launch_bounds__(256)
void cvt_zero_kernel(const float* __restrict__ x,
                     const float* __restrict__ w0, const float* __restrict__ w1,
                     const float* __restrict__ w2, const float* __restrict__ w3,
                     const float* __restrict__ w4, const float* __restrict__ w5,
                     const float* __restrict__ w6, const float* __restrict__ w7,
                     const float* __restrict__ w8,
                     const float* __restrict__ b0, const float* __restrict__ b1,
                     const float* __restrict__ b2, const float* __restrict__ b3,
                     const float* __restrict__ b4,
                     short* __restrict__ xb, short* __restrict__ wbf,
                     float* __restrict__ bcat, int* __restrict__ deg)
{
    if (blockIdx.x >= 4305) {
        int t = (blockIdx.x - 4305) * 256 + threadIdx.x;   // 0..8191
        ((int4*)deg)[t] = make_int4(0, 0, 0, 0);           // 32768 ints
        return;
    }
    long long t = (long long)blockIdx.x * 256 + threadIdx.x;
    long long i4 = t * 4;
    if (i4 < (long long)NM) {
        float4 v = *(const float4*)(x + i4);
        short4 o; o.x = f2bs(v.x); o.y = f2bs(v.y); o.z = f2bs(v.z); o.w = f2bs(v.w);
        *(short4*)(xb + i4) = o;
    } else {
        int j = (int)(i4 - (long long)NM);
        if (j < 212992) {
            const float* src; int off;
            if      (j <  16384) { src = w0; off = 0; }
            else if (j <  32768) { src = w1; off = 16384; }
            else if (j <  49152) { src = w2; off = 32768; }
            else if (j <  65536) { src = w3; off = 49152; }
            else if (j <  81920) { src = w4; off = 65536; }
            else if (j < 131072) { src = w5; off = 81920; }
            else if (j < 147456) { src = w6; off = 131072; }
            else if (j < 180224) { src = w7; off = 147456; }
            else                 { src = w8; off = 180224; }
            float4 v = *(const float4*)(src + (j - off));
            short4 o; o.x = f2bs(v.x); o.y = f2bs(v.y); o.z = f2bs(v.z); o.w = f2bs(v.w);
            *(short4*)(wbf + j) = o;
        } else if (j < 213632) {
            int jb = j - 212992;                 // 0..639
            int grp = jb >> 7, loc = jb & 127;
            const float* bs = (grp == 0) ? b0 : (grp == 1) ? b1 :
                              (grp == 2) ? b2 : (grp == 3) ? b3 : b4;
            float4 v = *(const float4*)(bs + loc);
            *(float4*)(bcat + jb) = v;
        }
    }
}

// ---------------------------------------------------------------------------
// k2: proj5 GEMM + hist tails (R6-proven).
// blocks [0,2560): GEMM; [2560,4608): histogram.
// ---------------------------------------------------------------------------
__global__ __launch_bounds__(256)
void proj5_hist_kernel(const short* __restrict__ xb, const short* __restrict__ wbf,
                       const float* __restrict__ bcat, const int* __restrict__ ei,
                       short* __restrict__ hin1b, short* __restrict__ kbv,
                       short* __restrict__ qvb, short* __restrict__ skipb,
                       int* __restrict__ deg)
{
    const int bid = blockIdx.x;
    if (bid >= 2560) {
        int e = (bid - 2560) * 256 + threadIdx.x;
        atomicAdd(&deg[ei[N_EDGES + e]], 1);
        return;
    }
    const int g  = bid / 512;
    const int my = bid % 512;
    const int lane = threadIdx.x & 63;
    const int wid  = threadIdx.x >> 6;
    const int m0 = my * 64 + (wid >> 1) * 32;
    const int n0 = (wid & 1) * 64;
    const int lrow = lane & 15;
    const int lk   = (lane >> 4) * 8;

    f32x4 acc[2][4] = {};
    const short* Ap = xb + (size_t)(m0 + lrow) * 128 + lk;
    const short* Wp = wbf + g * 16384 + (size_t)(n0 + lrow) * 128 + lk;
    #pragma unroll
    for (int ks = 0; ks < 128; ks += 32) {
        bf8 af[2], wf[4];
        af[0] = *(const bf8*)(Ap + ks);
        af[1] = *(const bf8*)(Ap + 16 * 128 + ks);
        #pragma unroll
        for (int j = 0; j < 4; ++j) wf[j] = *(const bf8*)(Wp + (size_t)j * 16 * 128 + ks);
        #pragma unroll
        for (int i = 0; i < 2; ++i)
            #pragma unroll
            for (int j = 0; j < 4; ++j)
                acc[i][j] = __builtin_amdgcn_mfma_f32_16x16x32_bf16(af[i], wf[j], acc[i][j], 0, 0, 0);
    }
    const int rbase = (lane >> 4) * 4;
    #pragma unroll
    for (int j = 0; j < 4; ++j) {
        int col = n0 + j * 16 + lrow;                 // 0..127
        float bcol = bcat[g * 128 + col];
        #pragma unroll
        for (int i = 0; i < 2; ++i)
            #pragma unroll
            for (int r = 0; r < 4; ++r) {
                int row = m0 + i * 16 + rbase + r;
                float v = acc[i][j][r] + bcol;
                if (g == 0)      { v = fmaxf(v, 0.f); hin1b[(size_t)row * 128 + col] = f2bs(v); }
                else if (g == 1) kbv[(size_t)row * 128 + col] = f2bs(v);
                else if (g == 2) qvb[(size_t)row * 256 + col * 2] = f2bs(v);
                else if (g == 3) qvb[(size_t)row * 256 + col * 2 + 1] = f2bs(v);
                else             skipb[(size_t)row * 128 + col] = f2bs(v);
            }
    }
}

// ---------------------------------------------------------------------------
// k3: scan
// ---------------------------------------------------------------------------
__global__ __launch_bounds__(1024)
void scan_kernel(const int* __restrict__ deg, int* __restrict__ offsets,
                 int* __restrict__ cursor)
{
    __shared__ int bufA[1024];
    __shared__ int bufB[1024];
    const int t = threadIdx.x;
    const int base = t * 32;

    int local[32];
    int run = 0;
    #pragma unroll
    for (int j = 0; j < 32; ++j) { local[j] = run; run += deg[base + j]; }

    int* src = bufA;
    int* dst = bufB;
    src[t] = run;
    __syncthreads();
    for (int off = 1; off < 1024; off <<= 1) {
        int v = src[t] + ((t >= off) ? src[t - off] : 0);
        dst[t] = v;
        __syncthreads();
        int* tmp = src; src = dst; dst = tmp;
    }
    int blockbase = (t == 0) ? 0 : src[t - 1];

    #pragma unroll
    for (int j = 0; j < 32; ++j) {
        int v = blockbase + local[j];
        offsets[base + j] = v;
        cursor[base + j]  = v;
    }
    if (t == 1023) offsets[N_NODES] = src[1023];
}

// ---------------------------------------------------------------------------
// k4: in_proj GEMM + scatter tails (R6-proven pairing, 58 us measured).
// blocks [0,1536): GEMM; [1536,3584): scatter.
// ---------------------------------------------------------------------------
__global__ __launch_bounds__(256)
void inproj_scatter_kernel(const short* __restrict__ hin1b, const short* __restrict__ wbf,
                           const float* __restrict__ bin, const int* __restrict__ ei,
                           int* __restrict__ cursor, int* __restrict__ csr_src,
                           short* __restrict__ qkvb, float qscale)
{
    const int bid = blockIdx.x;
    if (bid >= 1536) {
        int e = (bid - 1536) * 256 + threadIdx.x;
        int d = ei[N_EDGES + e];
        int pos = atomicAdd(&cursor[d], 1);
        csr_src[pos] = ei[e];
        return;
    }
    const int gx = bid % 3;
    const int my = bid / 3;
    const int lane = threadIdx.x & 63;
    const int wid  = threadIdx.x >> 6;
    const int m0 = my * 64 + (wid >> 1) * 32;
    const int n0 = (wid & 1) * 64;
    const int lrow = lane & 15;
    const int lk   = (lane >> 4) * 8;

    f32x4 acc[2][4] = {};
    const short* Ap = hin1b + (size_t)(m0 + lrow) * 128 + lk;
    const short* Wp = wbf + 81920 + (size_t)(gx * 128 + n0 + lrow) * 128 + lk;
    #pragma unroll
    for (int ks = 0; ks < 128; ks += 32) {
        bf8 af[2], wf[4];
        af[0] = *(const bf8*)(Ap + ks);
        af[1] = *(const bf8*)(Ap + 16 * 128 + ks);
        #pragma unroll
        for (int j = 0; j < 4; ++j) wf[j] = *(const bf8*)(Wp + (size_t)j * 16 * 128 + ks);
        #pragma unroll
        for (int i = 0; i < 2; ++i)
            #pragma unroll
            for (int j = 0; j < 4; ++j)
                acc[i][j] = __builtin_amdgcn_mfma_f32_16x16x32_bf16(af[i], wf[j], acc[i][j], 0, 0, 0);
    }
    const int rbase = (lane >> 4) * 4;
    #pragma unroll
    for (int j = 0; j < 4; ++j) {
        int col = gx * 128 + n0 + j * 16 + lrow;      // 0..383
        float bcol = bin[col];
        float sc = (col < 128) ? qscale : 1.0f;
        #pragma unroll
        for (int i = 0; i < 2; ++i)
            #pragma unroll
            for (int r = 0; r < 4; ++r) {
                int row = m0 + i * 16 + rbase + r;
                float v = (acc[i][j][r] + bcol) * sc;
                qkvb[(size_t)row * 384 + col] = f2bs(v);
            }
    }
}

// ---------------------------------------------------------------------------
// k5: FUSED attention + gather. 8704 blocks = 512*17.
// bid%17==0 -> attn block (bid/17); else gather block (independent work;
// MFMA-bound attn and latency-bound gather co-schedule on CUs).
// Attn LDS cut to 36 KB via 2-chunk K/V staging -> 4 blocks/CU.
// ---------------------------------------------------------------------------
__device__ __forceinline__ void lswap(unsigned int& X, unsigned int& Y, bool hi) {
    unsigned int Xs = (unsigned int)__shfl_xor((int)X, 32);
    unsigned int Ys = (unsigned int)__shfl_xor((int)Y, 32);
    unsigned int Xn = hi ? Ys : X;
    unsigned int Yn = hi ? Y  : Xs;
    X = Xn; Y = Yn;
}

__global__ __launch_bounds__(256)
void attn_gather_kernel(const short* __restrict__ qkv, short* __restrict__ ctx,
                        const unsigned int* __restrict__ kbu,
                        const uint2* __restrict__ qvu,
                        const unsigned int* __restrict__ skipu,
                        const unsigned int* __restrict__ hin1u,
                        const int* __restrict__ offsets, const int* __restrict__ csr_src,
                        const float* __restrict__ g1l, const float* __restrict__ b1l,
                        unsigned int* __restrict__ hlocal_u)
{
    __shared__ __align__(16) short ldsK[256 * 40];    // 20 KB, reused as O-stage
    __shared__ __align__(16) short ldsVt[32 * 256];   // 16 KB (32 rows x 512 B)

    const int bid = blockIdx.x;
    if (bid % 17 != 0) {
        // ---- gather: 4 nodes/block, one wave/node, 4-edge unroll (R6 body) ----
        const int gidx = bid - bid / 17 - 1;          // 0..8191
        const int d    = gidx * 4 + (threadIdx.x >> 6);
        const int lane = threadIdx.x & 63;            // owns cols 2l, 2l+1
        const float rs = 0.9999950000374998f;         // 1/sqrt(1+1e-5)

        float2 k2 = bs2f(kbu[(size_t)d * 64 + lane]);
        int i = offsets[d];
        const int end = offsets[d + 1];

        float ax = 0.f, ay = 0.f, cx = 0.f, cy = 0.f;
        for (; i + 4 <= end; i += 4) {
            int s0 = csr_src[i],     s1 = csr_src[i + 1];
            int s2 = csr_src[i + 2], s3 = csr_src[i + 3];
            uint2 w0 = qvu[(size_t)s0 * 64 + lane];
            uint2 w1 = qvu[(size_t)s1 * 64 + lane];
            uint2 w2 = qvu[(size_t)s2 * 64 + lane];
            uint2 w3 = qvu[(size_t)s3 * 64 + lane];
            float2 p0 = bs2f(w0.x), p1 = bs2f(w0.y);
            float2 p2 = bs2f(w1.x), p3 = bs2f(w1.y);
            float2 p4 = bs2f(w2.x), p5 = bs2f(w2.y);
            float2 p6 = bs2f(w3.x), p7 = bs2f(w3.y);
            ax += p0.y * __builtin_amdgcn_rcpf(1.0f + __expf(-(k2.x + p0.x)));
            ay += p1.y * __builtin_amdgcn_rcpf(1.0f + __expf(-(k2.y + p1.x)));
            cx += p2.y * __builtin_amdgcn_rcpf(1.0f + __expf(-(k2.x + p2.x)));
            cy += p3.y * __builtin_amdgcn_rcpf(1.0f + __expf(-(k2.y + p3.x)));
            ax += p4.y * __builtin_amdgcn_rcpf(1.0f + __expf(-(k2.x + p4.x)));
            ay += p5.y * __builtin_amdgcn_rcpf(1.0f + __expf(-(k2.y + p5.x)));
            cx += p6.y * __builtin_amdgcn_rcpf(1.0f + __expf(-(k2.x + p6.x)));
            cy += p7.y * __builtin_amdgcn_rcpf(1.0f + __expf(-(k2.y + p7.x)));
        }
        for (; i < end; ++i) {
            int s0 = csr_src[i];
            uint2 w0 = qvu[(size_t)s0 * 64 + lane];
            float2 p0 = bs2f(w0.x), p1 = bs2f(w0.y);
            ax += p0.y * __builtin_amdgcn_rcpf(1.0f + __expf(-(k2.x + p0.x)));
            ay += p1.y * __builtin_amdgcn_rcpf(1.0f + __expf(-(k2.y + p1.x)));
        }
        ax += cx; ay += cy;

        float2 sk = bs2f(skipu[(size_t)d * 64 + lane]);
        float2 hi = bs2f(hin1u[(size_t)d * 64 + lane]);
        float2 gv = *(const float2*)(g1l + lane * 2);
        float2 bt = *(const float2*)(b1l + lane * 2);
        float ox = (hi.x + sk.x + ax) * (gv.x * rs) + bt.x;
        float oy = (hi.y + sk.y + ay) * (gv.y * rs) + bt.y;
        hlocal_u[(size_t)d * 64 + lane] = pk2(ox, oy);
        return;
    }

    // ---- attention block ----
    const int blk  = bid / 17;           // 0..511 = (b, h, half)
    const int half = blk & 1;
    const int h    = (blk >> 1) & 3;
    const int b    = blk >> 3;
    const int tid  = threadIdx.x;
    const int lane = tid & 63;
    const int wid  = tid >> 6;
    const int lq = lane & 31;
    const int lg = lane >> 5;
    const size_t gbase = (size_t)(b * 512) * 384 + h * 32;

    // Q fragments in registers (q pre-scaled at in_proj)
    const int qoff = half * 256 + wid * 64;
    bf8 qf[2][2];
    #pragma unroll
    for (int qg = 0; qg < 2; ++qg)
        #pragma unroll
        for (int kh = 0; kh < 2; ++kh)
            qf[qg][kh] = *(const bf8*)(qkv + gbase +
                           (size_t)(qoff + qg * 32 + lq) * 384 + kh * 16 + lg * 8);

    const f32x16 Z16 = {0.f,0.f,0.f,0.f,0.f,0.f,0.f,0.f,0.f,0.f,0.f,0.f,0.f,0.f,0.f,0.f};
    f32x16 o[2] = {Z16, Z16};
    float mreg[2] = {-1e30f, -1e30f};
    float lreg[2] = {0.f, 0.f};
    const bool hiw = (lg != 0);

    for (int kc = 0; kc < 2; ++kc) {
        __syncthreads();                 // waves done with previous chunk
        // stage K chunk: keys kc*256..+255, row stride 40 shorts
        #pragma unroll
        for (int i = 0; i < 4; ++i) {
            int c = tid + i * 256;       // 0..1023
            int key = c >> 2, part = c & 3;
            bf8 v = *(const bf8*)(qkv + gbase +
                                  (size_t)(kc * 256 + key) * 384 + 128 + part * 8);
            *(bf8*)(ldsK + key * 40 + part * 8) = v;
        }
        // stage V^T chunk: row d (32), byte (key*2)^((d&7)<<4), 512 B rows
        if (tid < 128) {
            int p = tid;                 // pair (2p, 2p+1) within chunk
            const short* v0 = qkv + gbase + (size_t)(kc * 256 + 2 * p) * 384 + 256;
            const short* v1 = v0 + 384;
            bf8 r0[4], r1[4];
            #pragma unroll
            for (int i = 0; i < 4; ++i) { r0[i] = *(const bf8*)(v0 + i * 8);
                                          r1[i] = *(const bf8*)(v1 + i * 8); }
            #pragma unroll
            for (int d = 0; d < 32; ++d) {
                unsigned int w = ((unsigned int)(unsigned short)r0[d >> 3][d & 7]) |
                                 (((unsigned int)(unsigned short)r1[d >> 3][d & 7]) << 16);
                *(unsigned int*)((char*)ldsVt + d * 512 + ((4 * p) ^ ((d & 7) << 4))) = w;
            }
        }
        __syncthreads();

        for (int ktl = 0; ktl < 8; ++ktl) {
            bf8 ak[2], vt[2];
            #pragma unroll
            for (int kh = 0; kh < 2; ++kh) {
                ak[kh] = *(const bf8*)(ldsK + (ktl * 32 + lq) * 40 + kh * 16 + lg * 8);
                int kbyte = (ktl * 32 + kh * 16 + lg * 8) * 2;   // 0..511
                vt[kh] = *(const bf8*)((const char*)ldsVt + lq * 512 +
                                       (kbyte ^ ((lq & 7) << 4)));
            }
            #pragma unroll
            for (int qg = 0; qg < 2; ++qg) {
                f32x16 s = Z16;
                s = __builtin_amdgcn_mfma_f32_32x32x16_bf16(ak[0], qf[qg][0], s, 0, 0, 0);
                s = __builtin_amdgcn_mfma_f32_32x32x16_bf16(ak[1], qf[qg][1], s, 0, 0, 0);
                float t0 = fmaxf(fmaxf(s[0],  s[1]),  s[2]);
                float t1 = fmaxf(fmaxf(s[3],  s[4]),  s[5]);
                float t2 = fmaxf(fmaxf(s[6],  s[7]),  s[8]);
                float t3 = fmaxf(fmaxf(s[9],  s[10]), s[11]);
                float t4 = fmaxf(fmaxf(s[12], s[13]), s[14]);
                float mt = fmaxf(fmaxf(fmaxf(t0, t1), t2), fmaxf(fmaxf(t3, t4), s[15]));
                mt = fmaxf(mt, __shfl_xor(mt, 32));
                if (__any(mt > mreg[qg] + 8.0f)) {       // defer-max (T13)
                    float mnew = fmaxf(mreg[qg], mt);
                    float corr = __expf(mreg[qg] - mnew);
                    mreg[qg] = mnew;
                    lreg[qg] *= corr;
                    #pragma unroll
                    for (int r = 0; r < 16; ++r) o[qg][r] *= corr;
                }
                float m = mreg[qg];
                float p[16]; float ps = 0.f;
                #pragma unroll
                for (int r = 0; r < 16; ++r) { p[r] = __expf(s[r] - m); ps += p[r]; }
                ps += __shfl_xor(ps, 32);
                lreg[qg] += ps;
                unsigned int w0 = pk2(p[0],  p[1]),  w1 = pk2(p[2],  p[3]);
                unsigned int w2 = pk2(p[4],  p[5]),  w3 = pk2(p[6],  p[7]);
                unsigned int w4 = pk2(p[8],  p[9]),  w5 = pk2(p[10], p[11]);
                unsigned int w6 = pk2(p[12], p[13]), w7 = pk2(p[14], p[15]);
                lswap(w0, w2, hiw); lswap(w1, w3, hiw);
                lswap(w4, w6, hiw); lswap(w5, w7, hiw);
                union { unsigned int u[4]; bf8 v; } P0, P1;
                P0.u[0] = w0; P0.u[1] = w1; P0.u[2] = w2; P0.u[3] = w3;
                P1.u[0] = w4; P1.u[1] = w5; P1.u[2] = w6; P1.u[3] = w7;
                o[qg] = __builtin_amdgcn_mfma_f32_32x32x16_bf16(vt[0], P0.v, o[qg], 0, 0, 0);
                o[qg] = __builtin_amdgcn_mfma_f32_32x32x16_bf16(vt[1], P1.v, o[qg], 0, 0, 0);
            }
        }
    }

    // ---- epilogue: O^T regs -> LDS (swizzled) -> coalesced global bf16 ----
    __syncthreads();
    short* ldsO = ldsK;                    // [256 q][32 d], byte ^ ((q&7)<<3) : 16 KB
    #pragma unroll
    for (int qg = 0; qg < 2; ++qg) {
        float inv = 1.0f / lreg[qg];
        int ql = wid * 64 + qg * 32 + lq;
        #pragma unroll
        for (int b4 = 0; b4 < 4; ++b4) {
            short4 pkv;
            pkv.x = f2bs(o[qg][b4 * 4 + 0] * inv);
            pkv.y = f2bs(o[qg][b4 * 4 + 1] * inv);
            pkv.z = f2bs(o[qg][b4 * 4 + 2] * inv);
            pkv.w = f2bs(o[qg][b4 * 4 + 3] * inv);
            int dbyte = (8 * b4 + 4 * lg) * 2;
            *(short4*)((char*)ldsO + ql * 64 + (dbyte ^ ((ql & 7) << 3))) = pkv;
        }
    }
    __syncthreads();
    {
        int ql = tid;
        short* dst = ctx + (size_t)(b * 512 + half * 256 + ql) * 128 + h * 32;
        #pragma unroll
        for (int i = 0; i < 8; ++i) {
            short4 part = *(short4*)((char*)ldsO + ql * 64 + ((i * 8) ^ ((ql & 7) << 3)));
            *(short4*)(dst + i * 4) = part;
        }
    }
}

// ---------------------------------------------------------------------------
// k6: out_proj + combine: hbuf = hlocal + bn(hin1 + ctx@Wout^T + bout), bf16.
// ---------------------------------------------------------------------------
__global__ __launch_bounds__(256)
void outproj_combine_kernel(const short* __restrict__ ctxb, const short* __restrict__ wbf,
                            const float* __restrict__ bout,
                            const short* __restrict__ hin1b, const short* __restrict__ hlocb,
                            const float* __restrict__ gbn, const float* __restrict__ bbn,
                            short* __restrict__ hbufb)
{
    const int my = blockIdx.x;
    const int lane = threadIdx.x & 63;
    const int wid  = threadIdx.x >> 6;
    const int m0 = my * 64 + (wid >> 1) * 32;
    const int n0 = (wid & 1) * 64;
    const int lrow = lane & 15;
    const int lk   = (lane >> 4) * 8;
    const float rs = 0.9999950000374998f;

    f32x4 acc[2][4] = {};
    const short* Ap = ctxb + (size_t)(m0 + lrow) * 128 + lk;
    const short* Wp = wbf + 131072 + (size_t)(n0 + lrow) * 128 + lk;
    #pragma unroll
    for (int ks = 0; ks < 128; ks += 32) {
        bf8 af[2], wf[4];
        af[0] = *(const bf8*)(Ap + ks);
        af[1] = *(const bf8*)(Ap + 16 * 128 + ks);
        #pragma unroll
        for (int j = 0; j < 4; ++j) wf[j] = *(const bf8*)(Wp + (size_t)j * 16 * 128 + ks);
        #pragma unroll
        for (int i = 0; i < 2; ++i)
            #pragma unroll
            for (int j = 0; j < 4; ++j)
                acc[i][j] = __builtin_amdgcn_mfma_f32_16x16x32_bf16(af[i], wf[j], acc[i][j], 0, 0, 0);
    }
    const int rbase = (lane >> 4) * 4;
    #pragma unroll
    for (int j = 0; j < 4; ++j) {
        int col = n0 + j * 16 + lrow;
        float bcol = bout[col];
        float gsc = gbn[col] * rs;
        float bsc = bbn[col];
        #pragma unroll
        for (int i = 0; i < 2; ++i)
            #pragma unroll
            for (int r = 0; r < 4; ++r) {
                int row = m0 + i * 16 + rbase + r;
                size_t idx = (size_t)row * 128 + col;
                float v = acc[i][j][r] + bcol;
                float o = bs1f(hlocb[idx]) + (bs1f(hin1b[idx]) + v) * gsc + bsc;
                hbufb[idx] = f2bs(o);
            }
    }
}

// ---------------------------------------------------------------------------
// k7: fused FFN: ff1 = relu(hbuf@W1^T+b1) -> swizzled LDS; ff2 = ff1@W2^T+b2;
// out = bn(hbuf + ff2). One block per 64 rows.
// ---------------------------------------------------------------------------
__global__ __launch_bounds__(256)
void ff_fused_kernel(const short* __restrict__ hbufb, const short* __restrict__ wbf,
                     const float* __restrict__ b1, const float* __restrict__ b2,
                     const float* __restrict__ g2, const float* __restrict__ b2g,
                     float* __restrict__ out)
{
    __shared__ __align__(16) short ldsF[64 * 256];   // 32 KB
    const int my = blockIdx.x;
    const int lane = threadIdx.x & 63;
    const int wid  = threadIdx.x >> 6;
    const int lrow = lane & 15;
    const int lk   = (lane >> 4) * 8;
    const int rbase = (lane >> 4) * 4;
    const float rs = 0.9999950000374998f;

    // phase 1: ff1 tile 64x256 -> LDS (byte ^ ((row&7)<<4))
    {
        const int m0 = (wid >> 1) * 32;
        const int n0 = (wid & 1) * 128;
        f32x4 acc[2][8] = {};
        const short* Ap = hbufb + (size_t)(my * 64 + m0 + lrow) * 128 + lk;
        const short* Wp = wbf + 147456 + (size_t)(n0 + lrow) * 128 + lk;
        #pragma unroll
        for (int ks = 0; ks < 128; ks += 32) {
            bf8 af[2], wf[8];
            af[0] = *(const bf8*)(Ap + ks);
            af[1] = *(const bf8*)(Ap + 16 * 128 + ks);
            #pragma unroll
            for (int j = 0; j < 8; ++j) wf[j] = *(const bf8*)(Wp + (size_t)j * 16 * 128 + ks);
            #pragma unroll
            for (int i = 0; i < 2; ++i)
                #pragma unroll
                for (int j = 0; j < 8; ++j)
                    acc[i][j] = __builtin_amdgcn_mfma_f32_16x16x32_bf16(af[i], wf[j], acc[i][j], 0, 0, 0);
        }
        #pragma unroll
        for (int j = 0; j < 8; ++j) {
            int col = n0 + j * 16 + lrow;            // 0..255
            float bc = b1[col];
            #pragma unroll
            for (int i = 0; i < 2; ++i)
                #pragma unroll
                for (int r = 0; r < 4; ++r) {
                    int row = m0 + i * 16 + rbase + r;   // 0..63
                    float v = fmaxf(acc[i][j][r] + bc, 0.f);
                    int byte = (row * 512 + col * 2) ^ ((row & 7) << 4);
                    *(short*)((char*)ldsF + byte) = f2bs(v);
                }
        }
    }
    __syncthreads();
    // phase 2: ff2 + final BN
    {
        const int m0 = (wid >> 1) * 32;
        const int n0 = (wid & 1) * 64;
        f32x4 acc[2][4] = {};
        const short* Wp = wbf + 180224 + (size_t)(n0 + lrow) * 256 + lk;
        #pragma unroll
        for (int ks = 0; ks < 256; ks += 32) {
            bf8 af[2], wf[4];
            #pragma unroll
            for (int i = 0; i < 2; ++i) {
                int row = m0 + lrow + i * 16;
                int byte = (row * 512 + (ks + lk) * 2) ^ ((row & 7) << 4);
                af[i] = *(const bf8*)((const char*)ldsF + byte);
            }
            #pragma unroll
            for (int j = 0; j < 4; ++j) wf[j] = *(const bf8*)(Wp + (size_t)j * 16 * 256 + ks);
            #pragma unroll
            for (int i = 0; i < 2; ++i)
                #pragma unroll
                for (int j = 0; j < 4; ++j)
                    acc[i][j] = __builtin_amdgcn_mfma_f32_16x16x32_bf16(af[i], wf[j], acc[i][j], 0, 0, 0);
        }
        #pragma unroll
        for (int j = 0; j < 4; ++j) {
            int col = n0 + j * 16 + lrow;
            float bc = b2[col];
            float gsc = g2[col] * rs;
            float bsc = b2g[col];
            #pragma unroll
            for (int i = 0; i < 2; ++i)
                #pragma unroll
                for (int r = 0; r < 4; ++r) {
                    int row = my * 64 + m0 + i * 16 + rbase + r;
                    size_t idx = (size_t)row * 128 + col;
                    float v = acc[i][j][r] + bc;
                    out[idx] = (bs1f(hbufb[idx]) + v) * gsc + bsc;
                }
        }
    }
}

// ---------------------------------------------------------------------------
extern "C" void kernel_launch(void* const* d_in, const int* in_sizes, int n_in,
                              void* d_out, int out_size, void* d_ws, size_t ws_size,
                              hipStream_t stream)
{
    (void)in_sizes; (void)n_in; (void)out_size; (void)ws_size;

    const float* x    = (const float*)d_in[0];
    const int*   ei   = (const int*)d_in[1];
    const float* Wres = (const float*)d_in[3];
    const float* bres = (const float*)d_in[4];
    const float* Wk   = (const float*)d_in[5];
    const float* bk   = (const float*)d_in[6];
    const float* Wq   = (const float*)d_in[7];
    const float* bq   = (const float*)d_in[8];
    const float* Wv   = (const float*)d_in[9];
    const float* bv   = (const float*)d_in[10];
    const float* Wsk  = (const float*)d_in[11];
    const float* bsk  = (const float*)d_in[12];
    const float* g1l  = (const float*)d_in[13];
    const float* b1l  = (const float*)d_in[14];
    const float* g1a  = (const float*)d_in[15];
    const float* b1a  = (const float*)d_in[16];
    const float* Win  = (const float*)d_in[17];
    const float* bin  = (const float*)d_in[18];
    const float* Wout = (const float*)d_in[19];
    const float* bout = (const float*)d_in[20];
    const float* W1   = (const float*)d_in[21];
    const float* b1   = (const float*)d_in[22];
    const float* W2   = (const float*)d_in[23];
    const float* b2   = (const float*)d_in[24];
    const float* g2   = (const float*)d_in[25];
    const float* b2g  = (const float*)d_in[26];
    float* out = (float*)d_out;

    float* ws = (float*)d_ws;
    // ----- workspace layout (float-slot offsets), lifetimes k1..k7 -----
    short* hin1b = (short*)ws;                        // [0,0.5NM)  w:k2 r:k4,k5(gather),k6
    short* kbv   = (short*)(ws + NM / 2);             // [0.5NM,NM) w:k2 r:k5
    short* qvb   = (short*)(ws + NM);                 // [NM,2NM)   w:k2 r:k5 (q,v ilv)
    short* skipb = (short*)(ws + 2 * NM);             // [2NM,2.5NM) w:k2 r:k5
    short* xb    = (short*)(ws + 2 * NM + NM / 2);    // [2.5NM,3NM) w:k1 r:k2
    short* qkvb  = (short*)(ws + 3 * NM);             // [3NM,4.5NM) w:k4 r:k5(attn)
    short* hlocb = (short*)(ws + 4 * NM + NM / 2);    // [4.5NM,5NM) w:k5 r:k6
    // CSR ints [5NM, 5NM+622593 ints ~ 5.15NM) — live through k5 (gather reads)
    int* deg     = (int*)(ws + 5 * NM);               // w:k1(zero),k2(hist) r:k3
    int* offsets = deg + N_NODES;                     // w:k3 r:k5
    int* cursor  = offsets + N_NODES + 1;             // w:k3 rmw:k4
    int* csr_src = cursor + N_NODES;                  // w:k4 r:k5
    short* hbufb = (short*)(ws + 5 * NM + NM / 2);    // [5.5NM,6NM) w:k6 r:k7
    short* wbf   = (short*)(ws + 6 * NM);             // 212992 shorts = 106496 fslots
    float* bcat  = ws + 6 * NM + 106496;              // [640] f32
    short* ctxb  = (short*)(ws + 6 * NM + 110592);    // [N,128] bf16, w:k5(attn) r:k6
    // total extent: 6NM + 110592 + NM/2 fslots ~= 109.5 MB (<= 7NM used in R1/R2)

    dim3 blk(256);
    const float qscale = 0.17677669529663687f;    // 1/sqrt(32)

    // 1. cvt + zero deg
    cvt_zero_kernel<<<dim3(4337), blk, 0, stream>>>(
        x, Wres, Wk, Wq, Wv, Wsk, Win, Wout, W1, W2,
        bres, bk, bq, bv, bsk, xb, wbf, bcat, deg);

    // 2. proj5 GEMM + hist
    proj5_hist_kernel<<<dim3(4608), blk, 0, stream>>>(
        xb, wbf, bcat, ei, hin1b, kbv, qvb, skipb, deg);

    // 3. scan
    scan_kernel<<<dim3(1), dim3(1024), 0, stream>>>(deg, offsets, cursor);

    // 4. in_proj GEMM + scatter
    inproj_scatter_kernel<<<dim3(3584), blk, 0, stream>>>(
        hin1b, wbf, bin, ei, cursor, csr_src, qkvb, qscale);

    // 5. FUSED attention + gather (independent work, complementary pipes)
    attn_gather_kernel<<<dim3(8704), blk, 0, stream>>>(
        qkvb, ctxb,
        (const unsigned int*)kbv, (const uint2*)qvb, (const unsigned int*)skipb,
        (const unsigned int*)hin1b, offsets, csr_src, g1l, b1l,
        (unsigned int*)hlocb);

    // 6. out_proj + combine
    outproj_combine_kernel<<<dim3(512), blk, 0, stream>>>(
        ctxb, wbf, bout, hin1b, hlocb, g1a, b1a, hbufb);

    // 7. fused FFN + final BN
    ff_fused_kernel<<<dim3(512), blk, 0, stream>>>(
        hbufb, wbf, b1, b2, g2, b2g, out);
}

// Round 11
// 229.909 us; speedup vs baseline: 1.1476x; 1.1476x over previous
//
#include <hip/hip_runtime.h>
#include <math.h>

#define N_NODES 32768
#define N_EDGES 524288
#define DIM     128

static constexpr size_t NM = (size_t)N_NODES * DIM;   // 4194304

typedef __attribute__((ext_vector_type(8)))  short bf8;     // 8 bf16
typedef __attribute__((ext_vector_type(4)))  float f32x4;
typedef __attribute__((ext_vector_type(16))) float f32x16;

__device__ __forceinline__ short f2bs(float x) {
    union { float f; unsigned int u; } v; v.f = x;
    unsigned int r = v.u + 0x7fffu + ((v.u >> 16) & 1u);
    return (short)(r >> 16);
}
__device__ __forceinline__ unsigned int pk2(float a, float b) {
    return (unsigned int)(unsigned short)f2bs(a) |
           ((unsigned int)(unsigned short)f2bs(b) << 16);
}
__device__ __forceinline__ float2 bs2f(unsigned int u) {
    union { unsigned int a; float f; } lo, hi;
    lo.a = u << 16; hi.a = u & 0xffff0000u;
    float2 r; r.x = lo.f; r.y = hi.f; return r;
}
__device__ __forceinline__ float bs1f(short s) {
    union { unsigned int a; float f; } t;
    t.a = ((unsigned int)(unsigned short)s) << 16; return t.f;
}

// ---------------------------------------------------------------------------
// k1: cvt + zero-deg (R6-proven). x->bf16, weights->wbf, biases->bcat, deg=0.
// wbf short-offsets: Wres 0, Wk 16384, Wq 32768, Wv 49152, Wskip 65536,
//                    Win 81920, Wout 131072, W1 147456, W2 180224 (end 212992)
// ---------------------------------------------------------------------------
__global__ __launch_bounds__(256)
void cvt_zero_kernel(const float* __restrict__ x,
                     const float* __restrict__ w0, const float* __restrict__ w1,
                     const float* __restrict__ w2, const float* __restrict__ w3,
                     const float* __restrict__ w4, const float* __restrict__ w5,
                     const float* __restrict__ w6, const float* __restrict__ w7,
                     const float* __restrict__ w8,
                     const float* __restrict__ b0, const float* __restrict__ b1,
                     const float* __restrict__ b2, const float* __restrict__ b3,
                     const float* __restrict__ b4,
                     short* __restrict__ xb, short* __restrict__ wbf,
                     float* __restrict__ bcat, int* __restrict__ deg)
{
    if (blockIdx.x >= 4305) {
        int t = (blockIdx.x - 4305) * 256 + threadIdx.x;   // 0..8191
        ((int4*)deg)[t] = make_int4(0, 0, 0, 0);           // 32768 ints
        return;
    }
    long long t = (long long)blockIdx.x * 256 + threadIdx.x;
    long long i4 = t * 4;
    if (i4 < (long long)NM) {
        float4 v = *(const float4*)(x + i4);
        short4 o; o.x = f2bs(v.x); o.y = f2bs(v.y); o.z = f2bs(v.z); o.w = f2bs(v.w);
        *(short4*)(xb + i4) = o;
    } else {
        int j = (int)(i4 - (long long)NM);
        if (j < 212992) {
            const float* src; int off;
            if      (j <  16384) { src = w0; off = 0; }
            else if (j <  32768) { src = w1; off = 16384; }
            else if (j <  49152) { src = w2; off = 32768; }
            else if (j <  65536) { src = w3; off = 49152; }
            else if (j <  81920) { src = w4; off = 65536; }
            else if (j < 131072) { src = w5; off = 81920; }
            else if (j < 147456) { src = w6; off = 131072; }
            else if (j < 180224) { src = w7; off = 147456; }
            else                 { src = w8; off = 180224; }
            float4 v = *(const float4*)(src + (j - off));
            short4 o; o.x = f2bs(v.x); o.y = f2bs(v.y); o.z = f2bs(v.z); o.w = f2bs(v.w);
            *(short4*)(wbf + j) = o;
        } else if (j < 213632) {
            int jb = j - 212992;                 // 0..639
            int grp = jb >> 7, loc = jb & 127;
            const float* bs = (grp == 0) ? b0 : (grp == 1) ? b1 :
                              (grp == 2) ? b2 : (grp == 3) ? b3 : b4;
            float4 v = *(const float4*)(bs + loc);
            *(float4*)(bcat + jb) = v;
        }
    }
}

// ---------------------------------------------------------------------------
// k2: proj5 GEMM + hist tails (R6-proven).
// blocks [0,2560): GEMM; [2560,4608): histogram.
// ---------------------------------------------------------------------------
__global__ __launch_bounds__(256)
void proj5_hist_kernel(const short* __restrict__ xb, const short* __restrict__ wbf,
                       const float* __restrict__ bcat, const int* __restrict__ ei,
                       short* __restrict__ hin1b, short* __restrict__ kbv,
                       short* __restrict__ qvb, short* __restrict__ skipb,
                       int* __restrict__ deg)
{
    const int bid = blockIdx.x;
    if (bid >= 2560) {
        int e = (bid - 2560) * 256 + threadIdx.x;
        atomicAdd(&deg[ei[N_EDGES + e]], 1);
        return;
    }
    const int g  = bid / 512;
    const int my = bid % 512;
    const int lane = threadIdx.x & 63;
    const int wid  = threadIdx.x >> 6;
    const int m0 = my * 64 + (wid >> 1) * 32;
    const int n0 = (wid & 1) * 64;
    const int lrow = lane & 15;
    const int lk   = (lane >> 4) * 8;

    f32x4 acc[2][4] = {};
    const short* Ap = xb + (size_t)(m0 + lrow) * 128 + lk;
    const short* Wp = wbf + g * 16384 + (size_t)(n0 + lrow) * 128 + lk;
    #pragma unroll
    for (int ks = 0; ks < 128; ks += 32) {
        bf8 af[2], wf[4];
        af[0] = *(const bf8*)(Ap + ks);
        af[1] = *(const bf8*)(Ap + 16 * 128 + ks);
        #pragma unroll
        for (int j = 0; j < 4; ++j) wf[j] = *(const bf8*)(Wp + (size_t)j * 16 * 128 + ks);
        #pragma unroll
        for (int i = 0; i < 2; ++i)
            #pragma unroll
            for (int j = 0; j < 4; ++j)
                acc[i][j] = __builtin_amdgcn_mfma_f32_16x16x32_bf16(af[i], wf[j], acc[i][j], 0, 0, 0);
    }
    const int rbase = (lane >> 4) * 4;
    #pragma unroll
    for (int j = 0; j < 4; ++j) {
        int col = n0 + j * 16 + lrow;                 // 0..127
        float bcol = bcat[g * 128 + col];
        #pragma unroll
        for (int i = 0; i < 2; ++i)
            #pragma unroll
            for (int r = 0; r < 4; ++r) {
                int row = m0 + i * 16 + rbase + r;
                float v = acc[i][j][r] + bcol;
                if (g == 0)      { v = fmaxf(v, 0.f); hin1b[(size_t)row * 128 + col] = f2bs(v); }
                else if (g == 1) kbv[(size_t)row * 128 + col] = f2bs(v);
                else if (g == 2) qvb[(size_t)row * 256 + col * 2] = f2bs(v);
                else if (g == 3) qvb[(size_t)row * 256 + col * 2 + 1] = f2bs(v);
                else             skipb[(size_t)row * 128 + col] = f2bs(v);
            }
    }
}

// ---------------------------------------------------------------------------
// k3: scan
// ---------------------------------------------------------------------------
__global__ __launch_bounds__(1024)
void scan_kernel(const int* __restrict__ deg, int* __restrict__ offsets,
                 int* __restrict__ cursor)
{
    __shared__ int bufA[1024];
    __shared__ int bufB[1024];
    const int t = threadIdx.x;
    const int base = t * 32;

    int local[32];
    int run = 0;
    #pragma unroll
    for (int j = 0; j < 32; ++j) { local[j] = run; run += deg[base + j]; }

    int* src = bufA;
    int* dst = bufB;
    src[t] = run;
    __syncthreads();
    for (int off = 1; off < 1024; off <<= 1) {
        int v = src[t] + ((t >= off) ? src[t - off] : 0);
        dst[t] = v;
        __syncthreads();
        int* tmp = src; src = dst; dst = tmp;
    }
    int blockbase = (t == 0) ? 0 : src[t - 1];

    #pragma unroll
    for (int j = 0; j < 32; ++j) {
        int v = blockbase + local[j];
        offsets[base + j] = v;
        cursor[base + j]  = v;
    }
    if (t == 1023) offsets[N_NODES] = src[1023];
}

// ---------------------------------------------------------------------------
// k4: in_proj GEMM + scatter tails (R6-proven pairing).
// blocks [0,1536): GEMM; [1536,3584): scatter.
// ---------------------------------------------------------------------------
__global__ __launch_bounds__(256)
void inproj_scatter_kernel(const short* __restrict__ hin1b, const short* __restrict__ wbf,
                           const float* __restrict__ bin, const int* __restrict__ ei,
                           int* __restrict__ cursor, int* __restrict__ csr_src,
                           short* __restrict__ qkvb, float qscale)
{
    const int bid = blockIdx.x;
    if (bid >= 1536) {
        int e = (bid - 1536) * 256 + threadIdx.x;
        int d = ei[N_EDGES + e];
        int pos = atomicAdd(&cursor[d], 1);
        csr_src[pos] = ei[e];
        return;
    }
    const int gx = bid % 3;
    const int my = bid / 3;
    const int lane = threadIdx.x & 63;
    const int wid  = threadIdx.x >> 6;
    const int m0 = my * 64 + (wid >> 1) * 32;
    const int n0 = (wid & 1) * 64;
    const int lrow = lane & 15;
    const int lk   = (lane >> 4) * 8;

    f32x4 acc[2][4] = {};
    const short* Ap = hin1b + (size_t)(m0 + lrow) * 128 + lk;
    const short* Wp = wbf + 81920 + (size_t)(gx * 128 + n0 + lrow) * 128 + lk;
    #pragma unroll
    for (int ks = 0; ks < 128; ks += 32) {
        bf8 af[2], wf[4];
        af[0] = *(const bf8*)(Ap + ks);
        af[1] = *(const bf8*)(Ap + 16 * 128 + ks);
        #pragma unroll
        for (int j = 0; j < 4; ++j) wf[j] = *(const bf8*)(Wp + (size_t)j * 16 * 128 + ks);
        #pragma unroll
        for (int i = 0; i < 2; ++i)
            #pragma unroll
            for (int j = 0; j < 4; ++j)
                acc[i][j] = __builtin_amdgcn_mfma_f32_16x16x32_bf16(af[i], wf[j], acc[i][j], 0, 0, 0);
    }
    const int rbase = (lane >> 4) * 4;
    #pragma unroll
    for (int j = 0; j < 4; ++j) {
        int col = gx * 128 + n0 + j * 16 + lrow;      // 0..383
        float bcol = bin[col];
        float sc = (col < 128) ? qscale : 1.0f;
        #pragma unroll
        for (int i = 0; i < 2; ++i)
            #pragma unroll
            for (int r = 0; r < 4; ++r) {
                int row = m0 + i * 16 + rbase + r;
                float v = (acc[i][j][r] + bcol) * sc;
                qkvb[(size_t)row * 384 + col] = f2bs(v);
            }
    }
}

// ---------------------------------------------------------------------------
// k5: gather aggregation (R6 body + 8-edge unroll for MLP). One wave/node.
// ---------------------------------------------------------------------------
__global__ __launch_bounds__(256)
void gather_local_kernel(const unsigned int* __restrict__ kbu,
                         const uint2* __restrict__ qvu,
                         const unsigned int* __restrict__ skipu,
                         const unsigned int* __restrict__ hin1u,
                         const int* __restrict__ offsets, const int* __restrict__ csr_src,
                         const float* __restrict__ g, const float* __restrict__ beta,
                         unsigned int* __restrict__ hlocal_u)
{
    const int d    = blockIdx.x * 4 + (threadIdx.x >> 6);
    const int lane = threadIdx.x & 63;          // owns cols 2l, 2l+1
    const float rs = 0.9999950000374998f;       // 1/sqrt(1+1e-5)

    float2 k2 = bs2f(kbu[(size_t)d * 64 + lane]);
    int i = offsets[d];
    const int end = offsets[d + 1];

    float ax = 0.f, ay = 0.f, cx = 0.f, cy = 0.f;
    for (; i + 8 <= end; i += 8) {
        int s[8];
        #pragma unroll
        for (int u = 0; u < 8; ++u) s[u] = csr_src[i + u];
        uint2 w[8];
        #pragma unroll
        for (int u = 0; u < 8; ++u) w[u] = qvu[(size_t)s[u] * 64 + lane];
        #pragma unroll
        for (int u = 0; u < 8; ++u) {
            float2 pa = bs2f(w[u].x), pb = bs2f(w[u].y);
            if (u & 1) {
                cx += pa.y * __builtin_amdgcn_rcpf(1.0f + __expf(-(k2.x + pa.x)));
                cy += pb.y * __builtin_amdgcn_rcpf(1.0f + __expf(-(k2.y + pb.x)));
            } else {
                ax += pa.y * __builtin_amdgcn_rcpf(1.0f + __expf(-(k2.x + pa.x)));
                ay += pb.y * __builtin_amdgcn_rcpf(1.0f + __expf(-(k2.y + pb.x)));
            }
        }
    }
    for (; i + 4 <= end; i += 4) {
        int s0 = csr_src[i],     s1 = csr_src[i + 1];
        int s2 = csr_src[i + 2], s3 = csr_src[i + 3];
        uint2 w0 = qvu[(size_t)s0 * 64 + lane];
        uint2 w1 = qvu[(size_t)s1 * 64 + lane];
        uint2 w2 = qvu[(size_t)s2 * 64 + lane];
        uint2 w3 = qvu[(size_t)s3 * 64 + lane];
        float2 p0 = bs2f(w0.x), p1 = bs2f(w0.y);
        float2 p2 = bs2f(w1.x), p3 = bs2f(w1.y);
        float2 p4 = bs2f(w2.x), p5 = bs2f(w2.y);
        float2 p6 = bs2f(w3.x), p7 = bs2f(w3.y);
        ax += p0.y * __builtin_amdgcn_rcpf(1.0f + __expf(-(k2.x + p0.x)));
        ay += p1.y * __builtin_amdgcn_rcpf(1.0f + __expf(-(k2.y + p1.x)));
        cx += p2.y * __builtin_amdgcn_rcpf(1.0f + __expf(-(k2.x + p2.x)));
        cy += p3.y * __builtin_amdgcn_rcpf(1.0f + __expf(-(k2.y + p3.x)));
        ax += p4.y * __builtin_amdgcn_rcpf(1.0f + __expf(-(k2.x + p4.x)));
        ay += p5.y * __builtin_amdgcn_rcpf(1.0f + __expf(-(k2.y + p5.x)));
        cx += p6.y * __builtin_amdgcn_rcpf(1.0f + __expf(-(k2.x + p6.x)));
        cy += p7.y * __builtin_amdgcn_rcpf(1.0f + __expf(-(k2.y + p7.x)));
    }
    for (; i < end; ++i) {
        int s0 = csr_src[i];
        uint2 w0 = qvu[(size_t)s0 * 64 + lane];
        float2 p0 = bs2f(w0.x), p1 = bs2f(w0.y);
        ax += p0.y * __builtin_amdgcn_rcpf(1.0f + __expf(-(k2.x + p0.x)));
        ay += p1.y * __builtin_amdgcn_rcpf(1.0f + __expf(-(k2.y + p1.x)));
    }
    ax += cx; ay += cy;

    float2 sk = bs2f(skipu[(size_t)d * 64 + lane]);
    float2 hi = bs2f(hin1u[(size_t)d * 64 + lane]);
    float2 gv = *(const float2*)(g + lane * 2);
    float2 bt = *(const float2*)(beta + lane * 2);
    float ox = (hi.x + sk.x + ax) * (gv.x * rs) + bt.x;
    float oy = (hi.y + sk.y + ay) * (gv.y * rs) + bt.y;
    hlocal_u[(size_t)d * 64 + lane] = pk2(ox, oy);
}

// ---------------------------------------------------------------------------
// k6: MFMA flash attention (R6-proven). 512 blocks = (b, h, half).
// ---------------------------------------------------------------------------
__device__ __forceinline__ void lswap(unsigned int& X, unsigned int& Y, bool hi) {
    unsigned int Xs = (unsigned int)__shfl_xor((int)X, 32);
    unsigned int Ys = (unsigned int)__shfl_xor((int)Y, 32);
    unsigned int Xn = hi ? Ys : X;
    unsigned int Yn = hi ? Y  : Xs;
    X = Xn; Y = Yn;
}

__global__ __launch_bounds__(256)
void attn_mfma(const short* __restrict__ qkv, short* __restrict__ ctx)
{
    __shared__ __align__(16) short ldsK[512 * 40];    // 40 KB, reused as O
    __shared__ __align__(16) short ldsVt[32 * 512];   // 32 KB, swizzled

    const int blk  = blockIdx.x;         // B*H*2 = 512
    const int half = blk & 1;
    const int h    = (blk >> 1) & 3;
    const int b    = blk >> 3;
    const int tid  = threadIdx.x;
    const int lane = tid & 63;
    const int wid  = tid >> 6;
    const int lq = lane & 31;
    const int lg = lane >> 5;
    const size_t gbase = (size_t)(b * 512) * 384 + h * 32;

    #pragma unroll
    for (int i = 0; i < 8; ++i) {
        int c = tid + i * 256;
        int key = c >> 2, part = c & 3;
        bf8 v = *(const bf8*)(qkv + gbase + (size_t)key * 384 + 128 + part * 8);
        *(bf8*)(ldsK + key * 40 + part * 8) = v;
    }
    {
        int p = tid;
        const short* v0 = qkv + gbase + (size_t)(2 * p) * 384 + 256;
        const short* v1 = v0 + 384;
        bf8 r0[4], r1[4];
        #pragma unroll
        for (int i = 0; i < 4; ++i) { r0[i] = *(const bf8*)(v0 + i * 8);
                                      r1[i] = *(const bf8*)(v1 + i * 8); }
        #pragma unroll
        for (int d = 0; d < 32; ++d) {
            unsigned int w = ((unsigned int)(unsigned short)r0[d >> 3][d & 7]) |
                             (((unsigned int)(unsigned short)r1[d >> 3][d & 7]) << 16);
            *(unsigned int*)((char*)ldsVt + d * 1024 + ((4 * p) ^ ((d & 7) << 4))) = w;
        }
    }
    const int qoff = half * 256 + wid * 64;
    bf8 qf[2][2];
    #pragma unroll
    for (int qg = 0; qg < 2; ++qg)
        #pragma unroll
        for (int kh = 0; kh < 2; ++kh)
            qf[qg][kh] = *(const bf8*)(qkv + gbase +
                           (size_t)(qoff + qg * 32 + lq) * 384 + kh * 16 + lg * 8);
    __syncthreads();

    const f32x16 Z16 = {0.f,0.f,0.f,0.f,0.f,0.f,0.f,0.f,0.f,0.f,0.f,0.f,0.f,0.f,0.f,0.f};
    f32x16 o[2] = {Z16, Z16};
    float mreg[2] = {-1e30f, -1e30f};
    float lreg[2] = {0.f, 0.f};
    const bool hiw = (lg != 0);

    for (int kt = 0; kt < 16; ++kt) {
        bf8 ak[2], vt[2];
        #pragma unroll
        for (int kh = 0; kh < 2; ++kh) {
            ak[kh] = *(const bf8*)(ldsK + (kt * 32 + lq) * 40 + kh * 16 + lg * 8);
            int kbyte = (kt * 32 + kh * 16 + lg * 8) * 2;
            vt[kh] = *(const bf8*)((const char*)ldsVt + lq * 1024 +
                                   (kbyte ^ ((lq & 7) << 4)));
        }
        #pragma unroll
        for (int qg = 0; qg < 2; ++qg) {
            f32x16 s = Z16;
            s = __builtin_amdgcn_mfma_f32_32x32x16_bf16(ak[0], qf[qg][0], s, 0, 0, 0);
            s = __builtin_amdgcn_mfma_f32_32x32x16_bf16(ak[1], qf[qg][1], s, 0, 0, 0);
            float t0 = fmaxf(fmaxf(s[0],  s[1]),  s[2]);
            float t1 = fmaxf(fmaxf(s[3],  s[4]),  s[5]);
            float t2 = fmaxf(fmaxf(s[6],  s[7]),  s[8]);
            float t3 = fmaxf(fmaxf(s[9],  s[10]), s[11]);
            float t4 = fmaxf(fmaxf(s[12], s[13]), s[14]);
            float mt = fmaxf(fmaxf(fmaxf(t0, t1), t2), fmaxf(fmaxf(t3, t4), s[15]));
            mt = fmaxf(mt, __shfl_xor(mt, 32));
            if (__any(mt > mreg[qg] + 8.0f)) {       // defer-max (T13)
                float mnew = fmaxf(mreg[qg], mt);
                float corr = __expf(mreg[qg] - mnew);
                mreg[qg] = mnew;
                lreg[qg] *= corr;
                #pragma unroll
                for (int r = 0; r < 16; ++r) o[qg][r] *= corr;
            }
            float m = mreg[qg];
            float p[16]; float ps = 0.f;
            #pragma unroll
            for (int r = 0; r < 16; ++r) { p[r] = __expf(s[r] - m); ps += p[r]; }
            ps += __shfl_xor(ps, 32);
            lreg[qg] += ps;
            unsigned int w0 = pk2(p[0],  p[1]),  w1 = pk2(p[2],  p[3]);
            unsigned int w2 = pk2(p[4],  p[5]),  w3 = pk2(p[6],  p[7]);
            unsigned int w4 = pk2(p[8],  p[9]),  w5 = pk2(p[10], p[11]);
            unsigned int w6 = pk2(p[12], p[13]), w7 = pk2(p[14], p[15]);
            lswap(w0, w2, hiw); lswap(w1, w3, hiw);
            lswap(w4, w6, hiw); lswap(w5, w7, hiw);
            union { unsigned int u[4]; bf8 v; } P0, P1;
            P0.u[0] = w0; P0.u[1] = w1; P0.u[2] = w2; P0.u[3] = w3;
            P1.u[0] = w4; P1.u[1] = w5; P1.u[2] = w6; P1.u[3] = w7;
            o[qg] = __builtin_amdgcn_mfma_f32_32x32x16_bf16(vt[0], P0.v, o[qg], 0, 0, 0);
            o[qg] = __builtin_amdgcn_mfma_f32_32x32x16_bf16(vt[1], P1.v, o[qg], 0, 0, 0);
        }
    }

    __syncthreads();
    short* ldsO = ldsK;                    // [256 q][32 d], byte ^ ((q&7)<<3)
    #pragma unroll
    for (int qg = 0; qg < 2; ++qg) {
        float inv = 1.0f / lreg[qg];
        int ql = wid * 64 + qg * 32 + lq;
        #pragma unroll
        for (int b4 = 0; b4 < 4; ++b4) {
            short4 pkv;
            pkv.x = f2bs(o[qg][b4 * 4 + 0] * inv);
            pkv.y = f2bs(o[qg][b4 * 4 + 1] * inv);
            pkv.z = f2bs(o[qg][b4 * 4 + 2] * inv);
            pkv.w = f2bs(o[qg][b4 * 4 + 3] * inv);
            int dbyte = (8 * b4 + 4 * lg) * 2;
            *(short4*)((char*)ldsO + ql * 64 + (dbyte ^ ((ql & 7) << 3))) = pkv;
        }
    }
    __syncthreads();
    {
        int ql = tid;
        short* dst = ctx + (size_t)(b * 512 + half * 256 + ql) * 128 + h * 32;
        #pragma unroll
        for (int i = 0; i < 8; ++i) {
            short4 part = *(short4*)((char*)ldsO + ql * 64 + ((i * 8) ^ ((ql & 7) << 3)));
            *(short4*)(dst + i * 4) = part;
        }
    }
}

// ---------------------------------------------------------------------------
// k7: FUSED out_proj+combine+FFN+finalBN. One block per 64 rows (512 blocks).
// phase0: hbuf = hlocal + bn(hin1 + ctx@Wout^T + bout) -> ldsH (swizzled bf16)
// phase1: ff1 = relu(hbuf@W1^T + b1) -> ldsF (swizzled bf16)
// phase2: out = bn(hbuf + ff1@W2^T + b2)  (hbuf residual re-read from ldsH)
// Deletes the hbufb global round-trip (8 MB w + 16 MB r) and one launch.
// ---------------------------------------------------------------------------
__global__ __launch_bounds__(256)
void outproj_ff_kernel(const short* __restrict__ ctxb, const short* __restrict__ wbf,
                       const float* __restrict__ bout,
                       const short* __restrict__ hin1b, const short* __restrict__ hlocb,
                       const float* __restrict__ g1a, const float* __restrict__ b1a,
                       const float* __restrict__ b1, const float* __restrict__ b2,
                       const float* __restrict__ g2, const float* __restrict__ b2g,
                       float* __restrict__ out)
{
    __shared__ __align__(16) short ldsH[64 * 128];   // 16 KB, byte ^ ((row&7)<<4)
    __shared__ __align__(16) short ldsF[64 * 256];   // 32 KB, byte ^ ((row&7)<<4)
    const int my = blockIdx.x;
    const int lane = threadIdx.x & 63;
    const int wid  = threadIdx.x >> 6;
    const int lrow = lane & 15;
    const int lk   = (lane >> 4) * 8;
    const int rbase = (lane >> 4) * 4;
    const float rs = 0.9999950000374998f;

    // ---- phase 0: out_proj + combine -> ldsH ----
    {
        const int m0 = (wid >> 1) * 32;              // local row base (0/32)
        const int n0 = (wid & 1) * 64;
        f32x4 acc[2][4] = {};
        const short* Ap = ctxb + (size_t)(my * 64 + m0 + lrow) * 128 + lk;
        const short* Wp = wbf + 131072 + (size_t)(n0 + lrow) * 128 + lk;
        #pragma unroll
        for (int ks = 0; ks < 128; ks += 32) {
            bf8 af[2], wf[4];
            af[0] = *(const bf8*)(Ap + ks);
            af[1] = *(const bf8*)(Ap + 16 * 128 + ks);
            #pragma unroll
            for (int j = 0; j < 4; ++j) wf[j] = *(const bf8*)(Wp + (size_t)j * 16 * 128 + ks);
            #pragma unroll
            for (int i = 0; i < 2; ++i)
                #pragma unroll
                for (int j = 0; j < 4; ++j)
                    acc[i][j] = __builtin_amdgcn_mfma_f32_16x16x32_bf16(af[i], wf[j], acc[i][j], 0, 0, 0);
        }
        #pragma unroll
        for (int j = 0; j < 4; ++j) {
            int col = n0 + j * 16 + lrow;            // 0..127
            float bcol = bout[col];
            float gsc = g1a[col] * rs;
            float bsc = b1a[col];
            #pragma unroll
            for (int i = 0; i < 2; ++i)
                #pragma unroll
                for (int r = 0; r < 4; ++r) {
                    int rl = m0 + i * 16 + rbase + r;     // 0..63 local
                    size_t idx = (size_t)(my * 64 + rl) * 128 + col;
                    float v = acc[i][j][r] + bcol;
                    float o = bs1f(hlocb[idx]) + (bs1f(hin1b[idx]) + v) * gsc + bsc;
                    int byte = (rl * 256 + col * 2) ^ ((rl & 7) << 4);
                    *(short*)((char*)ldsH + byte) = f2bs(o);
                }
        }
    }
    __syncthreads();
    // ---- phase 1: ff1 -> ldsF ----
    {
        const int m0 = (wid >> 1) * 32;
        const int n0 = (wid & 1) * 128;
        f32x4 acc[2][8] = {};
        const short* Wp = wbf + 147456 + (size_t)(n0 + lrow) * 128 + lk;
        #pragma unroll
        for (int ks = 0; ks < 128; ks += 32) {
            bf8 af[2], wf[8];
            #pragma unroll
            for (int i = 0; i < 2; ++i) {
                int row = m0 + lrow + i * 16;
                int byte = (row * 256 + (ks + lk) * 2) ^ ((row & 7) << 4);
                af[i] = *(const bf8*)((const char*)ldsH + byte);
            }
            #pragma unroll
            for (int j = 0; j < 8; ++j) wf[j] = *(const bf8*)(Wp + (size_t)j * 16 * 128 + ks);
            #pragma unroll
            for (int i = 0; i < 2; ++i)
                #pragma unroll
                for (int j = 0; j < 8; ++j)
                    acc[i][j] = __builtin_amdgcn_mfma_f32_16x16x32_bf16(af[i], wf[j], acc[i][j], 0, 0, 0);
        }
        #pragma unroll
        for (int j = 0; j < 8; ++j) {
            int col = n0 + j * 16 + lrow;            // 0..255
            float bc = b1[col];
            #pragma unroll
            for (int i = 0; i < 2; ++i)
                #pragma unroll
                for (int r = 0; r < 4; ++r) {
                    int rl = m0 + i * 16 + rbase + r;    // 0..63
                    float v = fmaxf(acc[i][j][r] + bc, 0.f);
                    int byte = (rl * 512 + col * 2) ^ ((rl & 7) << 4);
                    *(short*)((char*)ldsF + byte) = f2bs(v);
                }
        }
    }
    __syncthreads();
    // ---- phase 2: ff2 + final BN (residual from ldsH) ----
    {
        const int m0 = (wid >> 1) * 32;
        const int n0 = (wid & 1) * 64;
        f32x4 acc[2][4] = {};
        const short* Wp = wbf + 180224 + (size_t)(n0 + lrow) * 256 + lk;
        #pragma unroll
        for (int ks = 0; ks < 256; ks += 32) {
            bf8 af[2], wf[4];
            #pragma unroll
            for (int i = 0; i < 2; ++i) {
                int row = m0 + lrow + i * 16;
                int byte = (row * 512 + (ks + lk) * 2) ^ ((row & 7) << 4);
                af[i] = *(const bf8*)((const char*)ldsF + byte);
            }
            #pragma unroll
            for (int j = 0; j < 4; ++j) wf[j] = *(const bf8*)(Wp + (size_t)j * 16 * 256 + ks);
            #pragma unroll
            for (int i = 0; i < 2; ++i)
                #pragma unroll
                for (int j = 0; j < 4; ++j)
                    acc[i][j] = __builtin_amdgcn_mfma_f32_16x16x32_bf16(af[i], wf[j], acc[i][j], 0, 0, 0);
        }
        #pragma unroll
        for (int j = 0; j < 4; ++j) {
            int col = n0 + j * 16 + lrow;
            float bc = b2[col];
            float gsc = g2[col] * rs;
            float bsc = b2g[col];
            #pragma unroll
            for (int i = 0; i < 2; ++i)
                #pragma unroll
                for (int r = 0; r < 4; ++r) {
                    int rl = m0 + i * 16 + rbase + r;
                    int hbyte = (rl * 256 + col * 2) ^ ((rl & 7) << 4);
                    float hres = bs1f(*(const short*)((const char*)ldsH + hbyte));
                    float v = acc[i][j][r] + bc;
                    out[(size_t)(my * 64 + rl) * 128 + col] = (hres + v) * gsc + bsc;
                }
        }
    }
}

// ---------------------------------------------------------------------------
extern "C" void kernel_launch(void* const* d_in, const int* in_sizes, int n_in,
                              void* d_out, int out_size, void* d_ws, size_t ws_size,
                              hipStream_t stream)
{
    (void)in_sizes; (void)n_in; (void)out_size; (void)ws_size;

    const float* x    = (const float*)d_in[0];
    const int*   ei   = (const int*)d_in[1];
    const float* Wres = (const float*)d_in[3];
    const float* bres = (const float*)d_in[4];
    const float* Wk   = (const float*)d_in[5];
    const float* bk   = (const float*)d_in[6];
    const float* Wq   = (const float*)d_in[7];
    const float* bq   = (const float*)d_in[8];
    const float* Wv   = (const float*)d_in[9];
    const float* bv   = (const float*)d_in[10];
    const float* Wsk  = (const float*)d_in[11];
    const float* bsk  = (const float*)d_in[12];
    const float* g1l  = (const float*)d_in[13];
    const float* b1l  = (const float*)d_in[14];
    const float* g1a  = (const float*)d_in[15];
    const float* b1a  = (const float*)d_in[16];
    const float* Win  = (const float*)d_in[17];
    const float* bin  = (const float*)d_in[18];
    const float* Wout = (const float*)d_in[19];
    const float* bout = (const float*)d_in[20];
    const float* W1   = (const float*)d_in[21];
    const float* b1   = (const float*)d_in[22];
    const float* W2   = (const float*)d_in[23];
    const float* b2   = (const float*)d_in[24];
    const float* g2   = (const float*)d_in[25];
    const float* b2g  = (const float*)d_in[26];
    float* out = (float*)d_out;

    float* ws = (float*)d_ws;
    // ----- workspace layout (float-slot offsets), lifetimes k1..k7 -----
    short* hin1b = (short*)ws;                        // [0,0.5NM)  w:k2 r:k4,k5,k7
    short* kbv   = (short*)(ws + NM / 2);             // [0.5NM,NM) w:k2 r:k5
    short* qvb   = (short*)(ws + NM);                 // [NM,2NM)   w:k2 r:k5 (q,v ilv)
    short* skipb = (short*)(ws + 2 * NM);             // [2NM,2.5NM) w:k2 r:k5
    short* xb    = (short*)(ws + 2 * NM + NM / 2);    // [2.5NM,3NM) w:k1 r:k2
    short* qkvb  = (short*)(ws + 3 * NM);             // [3NM,4.5NM) w:k4 r:k6
    short* hlocb = (short*)(ws + 4 * NM + NM / 2);    // [4.5NM,5NM) w:k5 r:k7
    // CSR ints overlay [5NM, 5NM+622593) — dead after k5; ctxb (w:k6) reuses it
    int* deg     = (int*)(ws + 5 * NM);               // w:k1(zero),k2(hist) r:k3
    int* offsets = deg + N_NODES;                     // w:k3 r:k5
    int* cursor  = offsets + N_NODES + 1;             // w:k3 rmw:k4
    int* csr_src = cursor + N_NODES;                  // w:k4 r:k5
    short* ctxb  = (short*)(ws + 5 * NM);             // [5NM,5.5NM) w:k6 r:k7
    short* wbf   = (short*)(ws + 6 * NM);             // 212992 shorts = 106496 fslots
    float* bcat  = ws + 6 * NM + 106496;              // [640] f32
    // total extent: 6NM + 107136 floats ≈ 101.1 MB

    dim3 blk(256);
    const float qscale = 0.17677669529663687f;    // 1/sqrt(32)

    // 1. cvt + zero deg
    cvt_zero_kernel<<<dim3(4337), blk, 0, stream>>>(
        x, Wres, Wk, Wq, Wv, Wsk, Win, Wout, W1, W2,
        bres, bk, bq, bv, bsk, xb, wbf, bcat, deg);

    // 2. proj5 GEMM + hist
    proj5_hist_kernel<<<dim3(4608), blk, 0, stream>>>(
        xb, wbf, bcat, ei, hin1b, kbv, qvb, skipb, deg);

    // 3. scan
    scan_kernel<<<dim3(1), dim3(1024), 0, stream>>>(deg, offsets, cursor);

    // 4. in_proj GEMM + scatter
    inproj_scatter_kernel<<<dim3(3584), blk, 0, stream>>>(
        hin1b, wbf, bin, ei, cursor, csr_src, qkvb, qscale);

    // 5. gather + skip + BN
    gather_local_kernel<<<dim3(N_NODES / 4), blk, 0, stream>>>(
        (const unsigned int*)kbv, (const uint2*)qvb, (const unsigned int*)skipb,
        (const unsigned int*)hin1b, offsets, csr_src, g1l, b1l,
        (unsigned int*)hlocb);

    // 6. attention
    attn_mfma<<<dim3(512), blk, 0, stream>>>(qkvb, ctxb);

    // 7. fused out_proj + combine + FFN + final BN
    outproj_ff_kernel<<<dim3(512), blk, 0, stream>>>(
        ctxb, wbf, bout, hin1b, hlocb, g1a, b1a, b1, b2, g2, b2g, out);
}

// Round 12
// 210.374 us; speedup vs baseline: 1.2541x; 1.0929x over previous
//
#include <hip/hip_runtime.h>
#include <math.h>

#define N_NODES 32768
#define N_EDGES 524288
#define DIM     128
#define CAP     80

static constexpr size_t NM = (size_t)N_NODES * DIM;   // 4194304

typedef __attribute__((ext_vector_type(8)))  short bf8;     // 8 bf16
typedef __attribute__((ext_vector_type(4)))  float f32x4;
typedef __attribute__((ext_vector_type(16))) float f32x16;

__device__ __forceinline__ short f2bs(float x) {
    union { float f; unsigned int u; } v; v.f = x;
    unsigned int r = v.u + 0x7fffu + ((v.u >> 16) & 1u);
    return (short)(r >> 16);
}
__device__ __forceinline__ unsigned int pk2(float a, float b) {
    return (unsigned int)(unsigned short)f2bs(a) |
           ((unsigned int)(unsigned short)f2bs(b) << 16);
}
__device__ __forceinline__ float2 bs2f(unsigned int u) {
    union { unsigned int a; float f; } lo, hi;
    lo.a = u << 16; hi.a = u & 0xffff0000u;
    float2 r; r.x = lo.f; r.y = hi.f; return r;
}
__device__ __forceinline__ float bs1f(short s) {
    union { unsigned int a; float f; } t;
    t.a = ((unsigned int)(unsigned short)s) << 16; return t.f;
}

// ---------------------------------------------------------------------------
// k1: cvt + slot-scatter. blocks [0,4305): x->bf16, weights->wbf, biases->bcat;
// blocks [4305,6353): slot scatter — pos=atomicAdd(deg[d]); slots[d*CAP+pos]=src.
// No hist, no scan. deg pre-zeroed by memset.
// wbf short-offsets: Wres 0, Wk 16384, Wq 32768, Wv 49152, Wskip 65536,
//                    Win 81920, Wout 131072, W1 147456, W2 180224 (end 212992)
// ---------------------------------------------------------------------------
__global__ __launch_bounds__(256)
void cvt_scatter_kernel(const float* __restrict__ x,
                        const float* __restrict__ w0, const float* __restrict__ w1,
                        const float* __restrict__ w2, const float* __restrict__ w3,
                        const float* __restrict__ w4, const float* __restrict__ w5,
                        const float* __restrict__ w6, const float* __restrict__ w7,
                        const float* __restrict__ w8,
                        const float* __restrict__ b0, const float* __restrict__ b1,
                        const float* __restrict__ b2, const float* __restrict__ b3,
                        const float* __restrict__ b4,
                        const int* __restrict__ ei,
                        short* __restrict__ xb, short* __restrict__ wbf,
                        float* __restrict__ bcat,
                        int* __restrict__ deg, unsigned short* __restrict__ slots)
{
    if (blockIdx.x >= 4305) {
        int e = (blockIdx.x - 4305) * 256 + threadIdx.x;   // 0..524287
        int d = ei[N_EDGES + e];
        int pos = atomicAdd(&deg[d], 1);
        if (pos < CAP) slots[d * CAP + pos] = (unsigned short)ei[e];
        return;
    }
    long long t = (long long)blockIdx.x * 256 + threadIdx.x;
    long long i4 = t * 4;
    if (i4 < (long long)NM) {
        float4 v = *(const float4*)(x + i4);
        short4 o; o.x = f2bs(v.x); o.y = f2bs(v.y); o.z = f2bs(v.z); o.w = f2bs(v.w);
        *(short4*)(xb + i4) = o;
    } else {
        int j = (int)(i4 - (long long)NM);
        if (j < 212992) {
            const float* src; int off;
            if      (j <  16384) { src = w0; off = 0; }
            else if (j <  32768) { src = w1; off = 16384; }
            else if (j <  49152) { src = w2; off = 32768; }
            else if (j <  65536) { src = w3; off = 49152; }
            else if (j <  81920) { src = w4; off = 65536; }
            else if (j < 131072) { src = w5; off = 81920; }
            else if (j < 147456) { src = w6; off = 131072; }
            else if (j < 180224) { src = w7; off = 147456; }
            else                 { src = w8; off = 180224; }
            float4 v = *(const float4*)(src + (j - off));
            short4 o; o.x = f2bs(v.x); o.y = f2bs(v.y); o.z = f2bs(v.z); o.w = f2bs(v.w);
            *(short4*)(wbf + j) = o;
        } else if (j < 213632) {
            int jb = j - 212992;                 // 0..639
            int grp = jb >> 7, loc = jb & 127;
            const float* bs = (grp == 0) ? b0 : (grp == 1) ? b1 :
                              (grp == 2) ? b2 : (grp == 3) ? b3 : b4;
            float4 v = *(const float4*)(bs + loc);
            *(float4*)(bcat + jb) = v;
        }
    }
}

// ---------------------------------------------------------------------------
// k2: proj5 (fused x-projections, 5 groups), clean.
// g0: relu->hin1b; g1: k; g2: q->qv[2c]; g3: v->qv[2c+1]; g4: skipb.
// ---------------------------------------------------------------------------
__global__ __launch_bounds__(256)
void proj5_kernel(const short* __restrict__ xb, const short* __restrict__ wbf,
                  const float* __restrict__ bcat,
                  short* __restrict__ hin1b, short* __restrict__ kbv,
                  short* __restrict__ qvb, short* __restrict__ skipb)
{
    const int g  = blockIdx.x / 512;
    const int my = blockIdx.x % 512;
    const int lane = threadIdx.x & 63;
    const int wid  = threadIdx.x >> 6;
    const int m0 = my * 64 + (wid >> 1) * 32;
    const int n0 = (wid & 1) * 64;
    const int lrow = lane & 15;
    const int lk   = (lane >> 4) * 8;

    f32x4 acc[2][4] = {};
    const short* Ap = xb + (size_t)(m0 + lrow) * 128 + lk;
    const short* Wp = wbf + g * 16384 + (size_t)(n0 + lrow) * 128 + lk;
    #pragma unroll
    for (int ks = 0; ks < 128; ks += 32) {
        bf8 af[2], wf[4];
        af[0] = *(const bf8*)(Ap + ks);
        af[1] = *(const bf8*)(Ap + 16 * 128 + ks);
        #pragma unroll
        for (int j = 0; j < 4; ++j) wf[j] = *(const bf8*)(Wp + (size_t)j * 16 * 128 + ks);
        #pragma unroll
        for (int i = 0; i < 2; ++i)
            #pragma unroll
            for (int j = 0; j < 4; ++j)
                acc[i][j] = __builtin_amdgcn_mfma_f32_16x16x32_bf16(af[i], wf[j], acc[i][j], 0, 0, 0);
    }
    const int rbase = (lane >> 4) * 4;
    #pragma unroll
    for (int j = 0; j < 4; ++j) {
        int col = n0 + j * 16 + lrow;                 // 0..127
        float bcol = bcat[g * 128 + col];
        #pragma unroll
        for (int i = 0; i < 2; ++i)
            #pragma unroll
            for (int r = 0; r < 4; ++r) {
                int row = m0 + i * 16 + rbase + r;
                float v = acc[i][j][r] + bcol;
                if (g == 0)      { v = fmaxf(v, 0.f); hin1b[(size_t)row * 128 + col] = f2bs(v); }
                else if (g == 1) kbv[(size_t)row * 128 + col] = f2bs(v);
                else if (g == 2) qvb[(size_t)row * 256 + col * 2] = f2bs(v);
                else if (g == 3) qvb[(size_t)row * 256 + col * 2 + 1] = f2bs(v);
                else             skipb[(size_t)row * 128 + col] = f2bs(v);
            }
    }
}

// ---------------------------------------------------------------------------
// k3: in_proj GEMM, clean (q-cols pre-scaled). 1536 blocks.
// ---------------------------------------------------------------------------
__global__ __launch_bounds__(256)
void inproj_kernel(const short* __restrict__ hin1b, const short* __restrict__ wbf,
                   const float* __restrict__ bin, short* __restrict__ qkvb,
                   float qscale)
{
    const int gx = blockIdx.x % 3;
    const int my = blockIdx.x / 3;
    const int lane = threadIdx.x & 63;
    const int wid  = threadIdx.x >> 6;
    const int m0 = my * 64 + (wid >> 1) * 32;
    const int n0 = (wid & 1) * 64;
    const int lrow = lane & 15;
    const int lk   = (lane >> 4) * 8;

    f32x4 acc[2][4] = {};
    const short* Ap = hin1b + (size_t)(m0 + lrow) * 128 + lk;
    const short* Wp = wbf + 81920 + (size_t)(gx * 128 + n0 + lrow) * 128 + lk;
    #pragma unroll
    for (int ks = 0; ks < 128; ks += 32) {
        bf8 af[2], wf[4];
        af[0] = *(const bf8*)(Ap + ks);
        af[1] = *(const bf8*)(Ap + 16 * 128 + ks);
        #pragma unroll
        for (int j = 0; j < 4; ++j) wf[j] = *(const bf8*)(Wp + (size_t)j * 16 * 128 + ks);
        #pragma unroll
        for (int i = 0; i < 2; ++i)
            #pragma unroll
            for (int j = 0; j < 4; ++j)
                acc[i][j] = __builtin_amdgcn_mfma_f32_16x16x32_bf16(af[i], wf[j], acc[i][j], 0, 0, 0);
    }
    const int rbase = (lane >> 4) * 4;
    #pragma unroll
    for (int j = 0; j < 4; ++j) {
        int col = gx * 128 + n0 + j * 16 + lrow;      // 0..383
        float bcol = bin[col];
        float sc = (col < 128) ? qscale : 1.0f;
        #pragma unroll
        for (int i = 0; i < 2; ++i)
            #pragma unroll
            for (int r = 0; r < 4; ++r) {
                int row = m0 + i * 16 + rbase + r;
                float v = (acc[i][j][r] + bcol) * sc;
                qkvb[(size_t)row * 384 + col] = f2bs(v);
            }
    }
}

// ---------------------------------------------------------------------------
// k4: gather aggregation via slot lists (no offsets). One wave/node,
// 8-edge unroll, rcp sigmoid, fused skip + BN, bf16 out.
// ---------------------------------------------------------------------------
__global__ __launch_bounds__(256)
void gather_local_kernel(const unsigned int* __restrict__ kbu,
                         const uint2* __restrict__ qvu,
                         const unsigned int* __restrict__ skipu,
                         const unsigned int* __restrict__ hin1u,
                         const int* __restrict__ deg,
                         const unsigned short* __restrict__ slots,
                         const float* __restrict__ g, const float* __restrict__ beta,
                         unsigned int* __restrict__ hlocal_u)
{
    const int d    = blockIdx.x * 4 + (threadIdx.x >> 6);
    const int lane = threadIdx.x & 63;          // owns cols 2l, 2l+1
    const float rs = 0.9999950000374998f;       // 1/sqrt(1+1e-5)

    float2 k2 = bs2f(kbu[(size_t)d * 64 + lane]);
    int dg = deg[d]; if (dg > CAP) dg = CAP;
    const unsigned short* sp = slots + (size_t)d * CAP;
    int i = 0;

    float ax = 0.f, ay = 0.f, cx = 0.f, cy = 0.f;
    for (; i + 8 <= dg; i += 8) {
        int s[8];
        #pragma unroll
        for (int u = 0; u < 8; ++u) s[u] = sp[i + u];
        uint2 w[8];
        #pragma unroll
        for (int u = 0; u < 8; ++u) w[u] = qvu[(size_t)s[u] * 64 + lane];
        #pragma unroll
        for (int u = 0; u < 8; ++u) {
            float2 pa = bs2f(w[u].x), pb = bs2f(w[u].y);
            if (u & 1) {
                cx += pa.y * __builtin_amdgcn_rcpf(1.0f + __expf(-(k2.x + pa.x)));
                cy += pb.y * __builtin_amdgcn_rcpf(1.0f + __expf(-(k2.y + pb.x)));
            } else {
                ax += pa.y * __builtin_amdgcn_rcpf(1.0f + __expf(-(k2.x + pa.x)));
                ay += pb.y * __builtin_amdgcn_rcpf(1.0f + __expf(-(k2.y + pb.x)));
            }
        }
    }
    for (; i + 4 <= dg; i += 4) {
        int s0 = sp[i], s1 = sp[i + 1], s2 = sp[i + 2], s3 = sp[i + 3];
        uint2 w0 = qvu[(size_t)s0 * 64 + lane];
        uint2 w1 = qvu[(size_t)s1 * 64 + lane];
        uint2 w2 = qvu[(size_t)s2 * 64 + lane];
        uint2 w3 = qvu[(size_t)s3 * 64 + lane];
        float2 p0 = bs2f(w0.x), p1 = bs2f(w0.y);
        float2 p2 = bs2f(w1.x), p3 = bs2f(w1.y);
        float2 p4 = bs2f(w2.x), p5 = bs2f(w2.y);
        float2 p6 = bs2f(w3.x), p7 = bs2f(w3.y);
        ax += p0.y * __builtin_amdgcn_rcpf(1.0f + __expf(-(k2.x + p0.x)));
        ay += p1.y * __builtin_amdgcn_rcpf(1.0f + __expf(-(k2.y + p1.x)));
        cx += p2.y * __builtin_amdgcn_rcpf(1.0f + __expf(-(k2.x + p2.x)));
        cy += p3.y * __builtin_amdgcn_rcpf(1.0f + __expf(-(k2.y + p3.x)));
        ax += p4.y * __builtin_amdgcn_rcpf(1.0f + __expf(-(k2.x + p4.x)));
        ay += p5.y * __builtin_amdgcn_rcpf(1.0f + __expf(-(k2.y + p5.x)));
        cx += p6.y * __builtin_amdgcn_rcpf(1.0f + __expf(-(k2.x + p6.x)));
        cy += p7.y * __builtin_amdgcn_rcpf(1.0f + __expf(-(k2.y + p7.x)));
    }
    for (; i < dg; ++i) {
        int s0 = sp[i];
        uint2 w0 = qvu[(size_t)s0 * 64 + lane];
        float2 p0 = bs2f(w0.x), p1 = bs2f(w0.y);
        ax += p0.y * __builtin_amdgcn_rcpf(1.0f + __expf(-(k2.x + p0.x)));
        ay += p1.y * __builtin_amdgcn_rcpf(1.0f + __expf(-(k2.y + p1.x)));
    }
    ax += cx; ay += cy;

    float2 sk = bs2f(skipu[(size_t)d * 64 + lane]);
    float2 hi = bs2f(hin1u[(size_t)d * 64 + lane]);
    float2 gv = *(const float2*)(g + lane * 2);
    float2 bt = *(const float2*)(beta + lane * 2);
    float ox = (hi.x + sk.x + ax) * (gv.x * rs) + bt.x;
    float oy = (hi.y + sk.y + ay) * (gv.y * rs) + bt.y;
    hlocal_u[(size_t)d * 64 + lane] = pk2(ox, oy);
}

// ---------------------------------------------------------------------------
// k5: MFMA flash attention (R6-proven). 512 blocks = (b, h, half).
// ---------------------------------------------------------------------------
__device__ __forceinline__ void lswap(unsigned int& X, unsigned int& Y, bool hi) {
    unsigned int Xs = (unsigned int)__shfl_xor((int)X, 32);
    unsigned int Ys = (unsigned int)__shfl_xor((int)Y, 32);
    unsigned int Xn = hi ? Ys : X;
    unsigned int Yn = hi ? Y  : Xs;
    X = Xn; Y = Yn;
}

__global__ __launch_bounds__(256)
void attn_mfma(const short* __restrict__ qkv, short* __restrict__ ctx)
{
    __shared__ __align__(16) short ldsK[512 * 40];    // 40 KB, reused as O
    __shared__ __align__(16) short ldsVt[32 * 512];   // 32 KB, swizzled

    const int blk  = blockIdx.x;         // B*H*2 = 512
    const int half = blk & 1;
    const int h    = (blk >> 1) & 3;
    const int b    = blk >> 3;
    const int tid  = threadIdx.x;
    const int lane = tid & 63;
    const int wid  = tid >> 6;
    const int lq = lane & 31;
    const int lg = lane >> 5;
    const size_t gbase = (size_t)(b * 512) * 384 + h * 32;

    #pragma unroll
    for (int i = 0; i < 8; ++i) {
        int c = tid + i * 256;
        int key = c >> 2, part = c & 3;
        bf8 v = *(const bf8*)(qkv + gbase + (size_t)key * 384 + 128 + part * 8);
        *(bf8*)(ldsK + key * 40 + part * 8) = v;
    }
    {
        int p = tid;
        const short* v0 = qkv + gbase + (size_t)(2 * p) * 384 + 256;
        const short* v1 = v0 + 384;
        bf8 r0[4], r1[4];
        #pragma unroll
        for (int i = 0; i < 4; ++i) { r0[i] = *(const bf8*)(v0 + i * 8);
                                      r1[i] = *(const bf8*)(v1 + i * 8); }
        #pragma unroll
        for (int d = 0; d < 32; ++d) {
            unsigned int w = ((unsigned int)(unsigned short)r0[d >> 3][d & 7]) |
                             (((unsigned int)(unsigned short)r1[d >> 3][d & 7]) << 16);
            *(unsigned int*)((char*)ldsVt + d * 1024 + ((4 * p) ^ ((d & 7) << 4))) = w;
        }
    }
    const int qoff = half * 256 + wid * 64;
    bf8 qf[2][2];
    #pragma unroll
    for (int qg = 0; qg < 2; ++qg)
        #pragma unroll
        for (int kh = 0; kh < 2; ++kh)
            qf[qg][kh] = *(const bf8*)(qkv + gbase +
                           (size_t)(qoff + qg * 32 + lq) * 384 + kh * 16 + lg * 8);
    __syncthreads();

    const f32x16 Z16 = {0.f,0.f,0.f,0.f,0.f,0.f,0.f,0.f,0.f,0.f,0.f,0.f,0.f,0.f,0.f,0.f};
    f32x16 o[2] = {Z16, Z16};
    float mreg[2] = {-1e30f, -1e30f};
    float lreg[2] = {0.f, 0.f};
    const bool hiw = (lg != 0);

    for (int kt = 0; kt < 16; ++kt) {
        bf8 ak[2], vt[2];
        #pragma unroll
        for (int kh = 0; kh < 2; ++kh) {
            ak[kh] = *(const bf8*)(ldsK + (kt * 32 + lq) * 40 + kh * 16 + lg * 8);
            int kbyte = (kt * 32 + kh * 16 + lg * 8) * 2;
            vt[kh] = *(const bf8*)((const char*)ldsVt + lq * 1024 +
                                   (kbyte ^ ((lq & 7) << 4)));
        }
        #pragma unroll
        for (int qg = 0; qg < 2; ++qg) {
            f32x16 s = Z16;
            s = __builtin_amdgcn_mfma_f32_32x32x16_bf16(ak[0], qf[qg][0], s, 0, 0, 0);
            s = __builtin_amdgcn_mfma_f32_32x32x16_bf16(ak[1], qf[qg][1], s, 0, 0, 0);
            float t0 = fmaxf(fmaxf(s[0],  s[1]),  s[2]);
            float t1 = fmaxf(fmaxf(s[3],  s[4]),  s[5]);
            float t2 = fmaxf(fmaxf(s[6],  s[7]),  s[8]);
            float t3 = fmaxf(fmaxf(s[9],  s[10]), s[11]);
            float t4 = fmaxf(fmaxf(s[12], s[13]), s[14]);
            float mt = fmaxf(fmaxf(fmaxf(t0, t1), t2), fmaxf(fmaxf(t3, t4), s[15]));
            mt = fmaxf(mt, __shfl_xor(mt, 32));
            if (__any(mt > mreg[qg] + 8.0f)) {       // defer-max (T13)
                float mnew = fmaxf(mreg[qg], mt);
                float corr = __expf(mreg[qg] - mnew);
                mreg[qg] = mnew;
                lreg[qg] *= corr;
                #pragma unroll
                for (int r = 0; r < 16; ++r) o[qg][r] *= corr;
            }
            float m = mreg[qg];
            float p[16]; float ps = 0.f;
            #pragma unroll
            for (int r = 0; r < 16; ++r) { p[r] = __expf(s[r] - m); ps += p[r]; }
            ps += __shfl_xor(ps, 32);
            lreg[qg] += ps;
            unsigned int w0 = pk2(p[0],  p[1]),  w1 = pk2(p[2],  p[3]);
            unsigned int w2 = pk2(p[4],  p[5]),  w3 = pk2(p[6],  p[7]);
            unsigned int w4 = pk2(p[8],  p[9]),  w5 = pk2(p[10], p[11]);
            unsigned int w6 = pk2(p[12], p[13]), w7 = pk2(p[14], p[15]);
            lswap(w0, w2, hiw); lswap(w1, w3, hiw);
            lswap(w4, w6, hiw); lswap(w5, w7, hiw);
            union { unsigned int u[4]; bf8 v; } P0, P1;
            P0.u[0] = w0; P0.u[1] = w1; P0.u[2] = w2; P0.u[3] = w3;
            P1.u[0] = w4; P1.u[1] = w5; P1.u[2] = w6; P1.u[3] = w7;
            o[qg] = __builtin_amdgcn_mfma_f32_32x32x16_bf16(vt[0], P0.v, o[qg], 0, 0, 0);
            o[qg] = __builtin_amdgcn_mfma_f32_32x32x16_bf16(vt[1], P1.v, o[qg], 0, 0, 0);
        }
    }

    __syncthreads();
    short* ldsO = ldsK;                    // [256 q][32 d], byte ^ ((q&7)<<3)
    #pragma unroll
    for (int qg = 0; qg < 2; ++qg) {
        float inv = 1.0f / lreg[qg];
        int ql = wid * 64 + qg * 32 + lq;
        #pragma unroll
        for (int b4 = 0; b4 < 4; ++b4) {
            short4 pkv;
            pkv.x = f2bs(o[qg][b4 * 4 + 0] * inv);
            pkv.y = f2bs(o[qg][b4 * 4 + 1] * inv);
            pkv.z = f2bs(o[qg][b4 * 4 + 2] * inv);
            pkv.w = f2bs(o[qg][b4 * 4 + 3] * inv);
            int dbyte = (8 * b4 + 4 * lg) * 2;
            *(short4*)((char*)ldsO + ql * 64 + (dbyte ^ ((ql & 7) << 3))) = pkv;
        }
    }
    __syncthreads();
    {
        int ql = tid;
        short* dst = ctx + (size_t)(b * 512 + half * 256 + ql) * 128 + h * 32;
        #pragma unroll
        for (int i = 0; i < 8; ++i) {
            short4 part = *(short4*)((char*)ldsO + ql * 64 + ((i * 8) ^ ((ql & 7) << 3)));
            *(short4*)(dst + i * 4) = part;
        }
    }
}

// ---------------------------------------------------------------------------
// k6: FUSED out_proj+combine+FFN+finalBN (R11-proven). 512 blocks.
// ---------------------------------------------------------------------------
__global__ __launch_bounds__(256)
void outproj_ff_kernel(const short* __restrict__ ctxb, const short* __restrict__ wbf,
                       const float* __restrict__ bout,
                       const short* __restrict__ hin1b, const short* __restrict__ hlocb,
                       const float* __restrict__ g1a, const float* __restrict__ b1a,
                       const float* __restrict__ b1, const float* __restrict__ b2,
                       const float* __restrict__ g2, const float* __restrict__ b2g,
                       float* __restrict__ out)
{
    __shared__ __align__(16) short ldsH[64 * 128];   // 16 KB, byte ^ ((row&7)<<4)
    __shared__ __align__(16) short ldsF[64 * 256];   // 32 KB, byte ^ ((row&7)<<4)
    const int my = blockIdx.x;
    const int lane = threadIdx.x & 63;
    const int wid  = threadIdx.x >> 6;
    const int lrow = lane & 15;
    const int lk   = (lane >> 4) * 8;
    const int rbase = (lane >> 4) * 4;
    const float rs = 0.9999950000374998f;

    // ---- phase 0: out_proj + combine -> ldsH ----
    {
        const int m0 = (wid >> 1) * 32;              // local row base (0/32)
        const int n0 = (wid & 1) * 64;
        f32x4 acc[2][4] = {};
        const short* Ap = ctxb + (size_t)(my * 64 + m0 + lrow) * 128 + lk;
        const short* Wp = wbf + 131072 + (size_t)(n0 + lrow) * 128 + lk;
        #pragma unroll
        for (int ks = 0; ks < 128; ks += 32) {
            bf8 af[2], wf[4];
            af[0] = *(const bf8*)(Ap + ks);
            af[1] = *(const bf8*)(Ap + 16 * 128 + ks);
            #pragma unroll
            for (int j = 0; j < 4; ++j) wf[j] = *(const bf8*)(Wp + (size_t)j * 16 * 128 + ks);
            #pragma unroll
            for (int i = 0; i < 2; ++i)
                #pragma unroll
                for (int j = 0; j < 4; ++j)
                    acc[i][j] = __builtin_amdgcn_mfma_f32_16x16x32_bf16(af[i], wf[j], acc[i][j], 0, 0, 0);
        }
        #pragma unroll
        for (int j = 0; j < 4; ++j) {
            int col = n0 + j * 16 + lrow;            // 0..127
            float bcol = bout[col];
            float gsc = g1a[col] * rs;
            float bsc = b1a[col];
            #pragma unroll
            for (int i = 0; i < 2; ++i)
                #pragma unroll
                for (int r = 0; r < 4; ++r) {
                    int rl = m0 + i * 16 + rbase + r;     // 0..63 local
                    size_t idx = (size_t)(my * 64 + rl) * 128 + col;
                    float v = acc[i][j][r] + bcol;
                    float o = bs1f(hlocb[idx]) + (bs1f(hin1b[idx]) + v) * gsc + bsc;
                    int byte = (rl * 256 + col * 2) ^ ((rl & 7) << 4);
                    *(short*)((char*)ldsH + byte) = f2bs(o);
                }
        }
    }
    __syncthreads();
    // ---- phase 1: ff1 -> ldsF ----
    {
        const int m0 = (wid >> 1) * 32;
        const int n0 = (wid & 1) * 128;
        f32x4 acc[2][8] = {};
        const short* Wp = wbf + 147456 + (size_t)(n0 + lrow) * 128 + lk;
        #pragma unroll
        for (int ks = 0; ks < 128; ks += 32) {
            bf8 af[2], wf[8];
            #pragma unroll
            for (int i = 0; i < 2; ++i) {
                int row = m0 + lrow + i * 16;
                int byte = (row * 256 + (ks + lk) * 2) ^ ((row & 7) << 4);
                af[i] = *(const bf8*)((const char*)ldsH + byte);
            }
            #pragma unroll
            for (int j = 0; j < 8; ++j) wf[j] = *(const bf8*)(Wp + (size_t)j * 16 * 128 + ks);
            #pragma unroll
            for (int i = 0; i < 2; ++i)
                #pragma unroll
                for (int j = 0; j < 8; ++j)
                    acc[i][j] = __builtin_amdgcn_mfma_f32_16x16x32_bf16(af[i], wf[j], acc[i][j], 0, 0, 0);
        }
        #pragma unroll
        for (int j = 0; j < 8; ++j) {
            int col = n0 + j * 16 + lrow;            // 0..255
            float bc = b1[col];
            #pragma unroll
            for (int i = 0; i < 2; ++i)
                #pragma unroll
                for (int r = 0; r < 4; ++r) {
                    int rl = m0 + i * 16 + rbase + r;    // 0..63
                    float v = fmaxf(acc[i][j][r] + bc, 0.f);
                    int byte = (rl * 512 + col * 2) ^ ((rl & 7) << 4);
                    *(short*)((char*)ldsF + byte) = f2bs(v);
                }
        }
    }
    __syncthreads();
    // ---- phase 2: ff2 + final BN (residual from ldsH) ----
    {
        const int m0 = (wid >> 1) * 32;
        const int n0 = (wid & 1) * 64;
        f32x4 acc[2][4] = {};
        const short* Wp = wbf + 180224 + (size_t)(n0 + lrow) * 256 + lk;
        #pragma unroll
        for (int ks = 0; ks < 256; ks += 32) {
            bf8 af[2], wf[4];
            #pragma unroll
            for (int i = 0; i < 2; ++i) {
                int row = m0 + lrow + i * 16;
                int byte = (row * 512 + (ks + lk) * 2) ^ ((row & 7) << 4);
                af[i] = *(const bf8*)((const char*)ldsF + byte);
            }
            #pragma unroll
            for (int j = 0; j < 4; ++j) wf[j] = *(const bf8*)(Wp + (size_t)j * 16 * 256 + ks);
            #pragma unroll
            for (int i = 0; i < 2; ++i)
                #pragma unroll
                for (int j = 0; j < 4; ++j)
                    acc[i][j] = __builtin_amdgcn_mfma_f32_16x16x32_bf16(af[i], wf[j], acc[i][j], 0, 0, 0);
        }
        #pragma unroll
        for (int j = 0; j < 4; ++j) {
            int col = n0 + j * 16 + lrow;
            float bc = b2[col];
            float gsc = g2[col] * rs;
            float bsc = b2g[col];
            #pragma unroll
            for (int i = 0; i < 2; ++i)
                #pragma unroll
                for (int r = 0; r < 4; ++r) {
                    int rl = m0 + i * 16 + rbase + r;
                    int hbyte = (rl * 256 + col * 2) ^ ((rl & 7) << 4);
                    float hres = bs1f(*(const short*)((const char*)ldsH + hbyte));
                    float v = acc[i][j][r] + bc;
                    out[(size_t)(my * 64 + rl) * 128 + col] = (hres + v) * gsc + bsc;
                }
        }
    }
}

// ---------------------------------------------------------------------------
extern "C" void kernel_launch(void* const* d_in, const int* in_sizes, int n_in,
                              void* d_out, int out_size, void* d_ws, size_t ws_size,
                              hipStream_t stream)
{
    (void)in_sizes; (void)n_in; (void)out_size; (void)ws_size;

    const float* x    = (const float*)d_in[0];
    const int*   ei   = (const int*)d_in[1];
    const float* Wres = (const float*)d_in[3];
    const float* bres = (const float*)d_in[4];
    const float* Wk   = (const float*)d_in[5];
    const float* bk   = (const float*)d_in[6];
    const float* Wq   = (const float*)d_in[7];
    const float* bq   = (const float*)d_in[8];
    const float* Wv   = (const float*)d_in[9];
    const float* bv   = (const float*)d_in[10];
    const float* Wsk  = (const float*)d_in[11];
    const float* bsk  = (const float*)d_in[12];
    const float* g1l  = (const float*)d_in[13];
    const float* b1l  = (const float*)d_in[14];
    const float* g1a  = (const float*)d_in[15];
    const float* b1a  = (const float*)d_in[16];
    const float* Win  = (const float*)d_in[17];
    const float* bin  = (const float*)d_in[18];
    const float* Wout = (const float*)d_in[19];
    const float* bout = (const float*)d_in[20];
    const float* W1   = (const float*)d_in[21];
    const float* b1   = (const float*)d_in[22];
    const float* W2   = (const float*)d_in[23];
    const float* b2   = (const float*)d_in[24];
    const float* g2   = (const float*)d_in[25];
    const float* b2g  = (const float*)d_in[26];
    float* out = (float*)d_out;

    float* ws = (float*)d_ws;
    // ----- workspace layout (float-slot offsets), lifetimes k1..k6 -----
    short* hin1b = (short*)ws;                        // [0,0.5NM)  w:k2 r:k3,k4,k6
    short* kbv   = (short*)(ws + NM / 2);             // [0.5NM,NM) w:k2 r:k4
    short* qvb   = (short*)(ws + NM);                 // [NM,2NM)   w:k2 r:k4 (q,v ilv)
    short* skipb = (short*)(ws + 2 * NM);             // [2NM,2.5NM) w:k2 r:k4
    short* xb    = (short*)(ws + 2 * NM + NM / 2);    // [2.5NM,3NM) w:k1 r:k2
    short* qkvb  = (short*)(ws + 3 * NM);             // [3NM,4.5NM) w:k3 r:k5
    short* hlocb = (short*)(ws + 4 * NM + NM / 2);    // [4.5NM,5NM) w:k4 r:k6
    // slot ints/ushorts overlay [5NM, ...) — dead after k4; ctxb (w:k5) reuses it
    int* deg = (int*)(ws + 5 * NM);                   // [N] w:memset, rmw:k1 r:k4
    unsigned short* slots = (unsigned short*)(deg + N_NODES);  // [N*CAP] w:k1 r:k4
    short* ctxb  = (short*)(ws + 5 * NM);             // [5NM,5.5NM) w:k5 r:k6
    short* hbuf_unused = nullptr; (void)hbuf_unused;
    short* wbf   = (short*)(ws + 6 * NM);             // 212992 shorts = 106496 fslots
    float* bcat  = ws + 6 * NM + 106496;              // [640] f32
    // slots end: 5NM + 32768 + 1310720 fslots < 5.5NM  ✓ (ctxb region is 2M fslots)
    // total extent: 6NM + 107136 floats ≈ 101.1 MB

    dim3 blk(256);
    const float qscale = 0.17677669529663687f;    // 1/sqrt(32)

    // 0. zero deg
    hipMemsetAsync((void*)deg, 0, N_NODES * sizeof(int), stream);

    // 1. cvt + slot scatter (no hist, no scan)
    cvt_scatter_kernel<<<dim3(6353), blk, 0, stream>>>(
        x, Wres, Wk, Wq, Wv, Wsk, Win, Wout, W1, W2,
        bres, bk, bq, bv, bsk, ei, xb, wbf, bcat, deg, slots);

    // 2. proj5 GEMM (clean)
    proj5_kernel<<<dim3(2560), blk, 0, stream>>>(
        xb, wbf, bcat, hin1b, kbv, qvb, skipb);

    // 3. in_proj GEMM (clean)
    inproj_kernel<<<dim3(1536), blk, 0, stream>>>(
        hin1b, wbf, bin, qkvb, qscale);

    // 4. gather + skip + BN (slot lists)
    gather_local_kernel<<<dim3(N_NODES / 4), blk, 0, stream>>>(
        (const unsigned int*)kbv, (const uint2*)qvb, (const unsigned int*)skipb,
        (const unsigned int*)hin1b, deg, slots, g1l, b1l,
        (unsigned int*)hlocb);

    // 5. attention
    attn_mfma<<<dim3(512), blk, 0, stream>>>(qkvb, ctxb);

    // 6. fused out_proj + combine + FFN + final BN
    outproj_ff_kernel<<<dim3(512), blk, 0, stream>>>(
        ctxb, wbf, bout, hin1b, hlocb, g1a, b1a, b1, b2, g2, b2g, out);
}

// Round 13
// 205.285 us; speedup vs baseline: 1.2852x; 1.0248x over previous
//
#include <hip/hip_runtime.h>
#include <math.h>

#define N_NODES 32768
#define N_EDGES 524288
#define DIM     128
#define CAP     80

static constexpr size_t NM = (size_t)N_NODES * DIM;   // 4194304

typedef __attribute__((ext_vector_type(8)))  short bf8;     // 8 bf16
typedef __attribute__((ext_vector_type(4)))  float f32x4;
typedef __attribute__((ext_vector_type(16))) float f32x16;

__device__ __forceinline__ short f2bs(float x) {
    union { float f; unsigned int u; } v; v.f = x;
    unsigned int r = v.u + 0x7fffu + ((v.u >> 16) & 1u);
    return (short)(r >> 16);
}
__device__ __forceinline__ unsigned int pk2(float a, float b) {
    return (unsigned int)(unsigned short)f2bs(a) |
           ((unsigned int)(unsigned short)f2bs(b) << 16);
}
__device__ __forceinline__ float2 bs2f(unsigned int u) {
    union { unsigned int a; float f; } lo, hi;
    lo.a = u << 16; hi.a = u & 0xffff0000u;
    float2 r; r.x = lo.f; r.y = hi.f; return r;
}
__device__ __forceinline__ float bs1f(short s) {
    union { unsigned int a; float f; } t;
    t.a = ((unsigned int)(unsigned short)s) << 16; return t.f;
}

// ---------------------------------------------------------------------------
// k1: scatter + cvt. blocks [0,2048): slot scatter (FIRST, so its atomic
// latency chain overlaps the streaming cvt blocks); blocks [2048,6353):
// x->bf16, weights->wbf, biases->bcat. deg pre-zeroed by memset.
// wbf short-offsets: Wres 0, Wk 16384, Wq 32768, Wv 49152, Wskip 65536,
//                    Win 81920, Wout 131072, W1 147456, W2 180224 (end 212992)
// ---------------------------------------------------------------------------
__global__ __launch_bounds__(256)
void cvt_scatter_kernel(const float* __restrict__ x,
                        const float* __restrict__ w0, const float* __restrict__ w1,
                        const float* __restrict__ w2, const float* __restrict__ w3,
                        const float* __restrict__ w4, const float* __restrict__ w5,
                        const float* __restrict__ w6, const float* __restrict__ w7,
                        const float* __restrict__ w8,
                        const float* __restrict__ b0, const float* __restrict__ b1,
                        const float* __restrict__ b2, const float* __restrict__ b3,
                        const float* __restrict__ b4,
                        const int* __restrict__ ei,
                        short* __restrict__ xb, short* __restrict__ wbf,
                        float* __restrict__ bcat,
                        int* __restrict__ deg, unsigned short* __restrict__ slots)
{
    if (blockIdx.x < 2048) {
        int e = blockIdx.x * 256 + threadIdx.x;            // 0..524287
        int d = ei[N_EDGES + e];
        int pos = atomicAdd(&deg[d], 1);
        if (pos < CAP) slots[d * CAP + pos] = (unsigned short)ei[e];
        return;
    }
    long long t = (long long)(blockIdx.x - 2048) * 256 + threadIdx.x;
    long long i4 = t * 4;
    if (i4 < (long long)NM) {
        float4 v = *(const float4*)(x + i4);
        short4 o; o.x = f2bs(v.x); o.y = f2bs(v.y); o.z = f2bs(v.z); o.w = f2bs(v.w);
        *(short4*)(xb + i4) = o;
    } else {
        int j = (int)(i4 - (long long)NM);
        if (j < 212992) {
            const float* src; int off;
            if      (j <  16384) { src = w0; off = 0; }
            else if (j <  32768) { src = w1; off = 16384; }
            else if (j <  49152) { src = w2; off = 32768; }
            else if (j <  65536) { src = w3; off = 49152; }
            else if (j <  81920) { src = w4; off = 65536; }
            else if (j < 131072) { src = w5; off = 81920; }
            else if (j < 147456) { src = w6; off = 131072; }
            else if (j < 180224) { src = w7; off = 147456; }
            else                 { src = w8; off = 180224; }
            float4 v = *(const float4*)(src + (j - off));
            short4 o; o.x = f2bs(v.x); o.y = f2bs(v.y); o.z = f2bs(v.z); o.w = f2bs(v.w);
            *(short4*)(wbf + j) = o;
        } else if (j < 213632) {
            int jb = j - 212992;                 // 0..639
            int grp = jb >> 7, loc = jb & 127;
            const float* bs = (grp == 0) ? b0 : (grp == 1) ? b1 :
                              (grp == 2) ? b2 : (grp == 3) ? b3 : b4;
            float4 v = *(const float4*)(bs + loc);
            *(float4*)(bcat + jb) = v;
        }
    }
}

// ---------------------------------------------------------------------------
// k2: proj5 (fused x-projections, 5 groups), clean.
// g0: relu->hin1b; g1: k; g2: q->qv[2c]; g3: v->qv[2c+1]; g4: skipb.
// ---------------------------------------------------------------------------
__global__ __launch_bounds__(256)
void proj5_kernel(const short* __restrict__ xb, const short* __restrict__ wbf,
                  const float* __restrict__ bcat,
                  short* __restrict__ hin1b, short* __restrict__ kbv,
                  short* __restrict__ qvb, short* __restrict__ skipb)
{
    const int g  = blockIdx.x / 512;
    const int my = blockIdx.x % 512;
    const int lane = threadIdx.x & 63;
    const int wid  = threadIdx.x >> 6;
    const int m0 = my * 64 + (wid >> 1) * 32;
    const int n0 = (wid & 1) * 64;
    const int lrow = lane & 15;
    const int lk   = (lane >> 4) * 8;

    f32x4 acc[2][4] = {};
    const short* Ap = xb + (size_t)(m0 + lrow) * 128 + lk;
    const short* Wp = wbf + g * 16384 + (size_t)(n0 + lrow) * 128 + lk;
    #pragma unroll
    for (int ks = 0; ks < 128; ks += 32) {
        bf8 af[2], wf[4];
        af[0] = *(const bf8*)(Ap + ks);
        af[1] = *(const bf8*)(Ap + 16 * 128 + ks);
        #pragma unroll
        for (int j = 0; j < 4; ++j) wf[j] = *(const bf8*)(Wp + (size_t)j * 16 * 128 + ks);
        #pragma unroll
        for (int i = 0; i < 2; ++i)
            #pragma unroll
            for (int j = 0; j < 4; ++j)
                acc[i][j] = __builtin_amdgcn_mfma_f32_16x16x32_bf16(af[i], wf[j], acc[i][j], 0, 0, 0);
    }
    const int rbase = (lane >> 4) * 4;
    #pragma unroll
    for (int j = 0; j < 4; ++j) {
        int col = n0 + j * 16 + lrow;                 // 0..127
        float bcol = bcat[g * 128 + col];
        #pragma unroll
        for (int i = 0; i < 2; ++i)
            #pragma unroll
            for (int r = 0; r < 4; ++r) {
                int row = m0 + i * 16 + rbase + r;
                float v = acc[i][j][r] + bcol;
                if (g == 0)      { v = fmaxf(v, 0.f); hin1b[(size_t)row * 128 + col] = f2bs(v); }
                else if (g == 1) kbv[(size_t)row * 128 + col] = f2bs(v);
                else if (g == 2) qvb[(size_t)row * 256 + col * 2] = f2bs(v);
                else if (g == 3) qvb[(size_t)row * 256 + col * 2 + 1] = f2bs(v);
                else             skipb[(size_t)row * 128 + col] = f2bs(v);
            }
    }
}

// ---------------------------------------------------------------------------
// k3: in_proj GEMM, clean (q-cols pre-scaled by qscale*log2e). 1536 blocks.
// ---------------------------------------------------------------------------
__global__ __launch_bounds__(256)
void inproj_kernel(const short* __restrict__ hin1b, const short* __restrict__ wbf,
                   const float* __restrict__ bin, short* __restrict__ qkvb,
                   float qscale)
{
    const int gx = blockIdx.x % 3;
    const int my = blockIdx.x / 3;
    const int lane = threadIdx.x & 63;
    const int wid  = threadIdx.x >> 6;
    const int m0 = my * 64 + (wid >> 1) * 32;
    const int n0 = (wid & 1) * 64;
    const int lrow = lane & 15;
    const int lk   = (lane >> 4) * 8;

    f32x4 acc[2][4] = {};
    const short* Ap = hin1b + (size_t)(m0 + lrow) * 128 + lk;
    const short* Wp = wbf + 81920 + (size_t)(gx * 128 + n0 + lrow) * 128 + lk;
    #pragma unroll
    for (int ks = 0; ks < 128; ks += 32) {
        bf8 af[2], wf[4];
        af[0] = *(const bf8*)(Ap + ks);
        af[1] = *(const bf8*)(Ap + 16 * 128 + ks);
        #pragma unroll
        for (int j = 0; j < 4; ++j) wf[j] = *(const bf8*)(Wp + (size_t)j * 16 * 128 + ks);
        #pragma unroll
        for (int i = 0; i < 2; ++i)
            #pragma unroll
            for (int j = 0; j < 4; ++j)
                acc[i][j] = __builtin_amdgcn_mfma_f32_16x16x32_bf16(af[i], wf[j], acc[i][j], 0, 0, 0);
    }
    const int rbase = (lane >> 4) * 4;
    #pragma unroll
    for (int j = 0; j < 4; ++j) {
        int col = gx * 128 + n0 + j * 16 + lrow;      // 0..383
        float bcol = bin[col];
        float sc = (col < 128) ? qscale : 1.0f;
        #pragma unroll
        for (int i = 0; i < 2; ++i)
            #pragma unroll
            for (int r = 0; r < 4; ++r) {
                int row = m0 + i * 16 + rbase + r;
                float v = (acc[i][j][r] + bcol) * sc;
                qkvb[(size_t)row * 384 + col] = f2bs(v);
            }
    }
}

// ---------------------------------------------------------------------------
// k4: gather aggregation via slot lists. One wave/node, 8-edge unroll.
// ---------------------------------------------------------------------------
__global__ __launch_bounds__(256)
void gather_local_kernel(const unsigned int* __restrict__ kbu,
                         const uint2* __restrict__ qvu,
                         const unsigned int* __restrict__ skipu,
                         const unsigned int* __restrict__ hin1u,
                         const int* __restrict__ deg,
                         const unsigned short* __restrict__ slots,
                         const float* __restrict__ g, const float* __restrict__ beta,
                         unsigned int* __restrict__ hlocal_u)
{
    const int d    = blockIdx.x * 4 + (threadIdx.x >> 6);
    const int lane = threadIdx.x & 63;          // owns cols 2l, 2l+1
    const float rs = 0.9999950000374998f;       // 1/sqrt(1+1e-5)

    float2 k2 = bs2f(kbu[(size_t)d * 64 + lane]);
    int dg = deg[d]; if (dg > CAP) dg = CAP;
    const unsigned short* sp = slots + (size_t)d * CAP;
    int i = 0;

    float ax = 0.f, ay = 0.f, cx = 0.f, cy = 0.f;
    for (; i + 8 <= dg; i += 8) {
        int s[8];
        #pragma unroll
        for (int u = 0; u < 8; ++u) s[u] = sp[i + u];
        uint2 w[8];
        #pragma unroll
        for (int u = 0; u < 8; ++u) w[u] = qvu[(size_t)s[u] * 64 + lane];
        #pragma unroll
        for (int u = 0; u < 8; ++u) {
            float2 pa = bs2f(w[u].x), pb = bs2f(w[u].y);
            if (u & 1) {
                cx += pa.y * __builtin_amdgcn_rcpf(1.0f + __expf(-(k2.x + pa.x)));
                cy += pb.y * __builtin_amdgcn_rcpf(1.0f + __expf(-(k2.y + pb.x)));
            } else {
                ax += pa.y * __builtin_amdgcn_rcpf(1.0f + __expf(-(k2.x + pa.x)));
                ay += pb.y * __builtin_amdgcn_rcpf(1.0f + __expf(-(k2.y + pb.x)));
            }
        }
    }
    for (; i + 4 <= dg; i += 4) {
        int s0 = sp[i], s1 = sp[i + 1], s2 = sp[i + 2], s3 = sp[i + 3];
        uint2 w0 = qvu[(size_t)s0 * 64 + lane];
        uint2 w1 = qvu[(size_t)s1 * 64 + lane];
        uint2 w2 = qvu[(size_t)s2 * 64 + lane];
        uint2 w3 = qvu[(size_t)s3 * 64 + lane];
        float2 p0 = bs2f(w0.x), p1 = bs2f(w0.y);
        float2 p2 = bs2f(w1.x), p3 = bs2f(w1.y);
        float2 p4 = bs2f(w2.x), p5 = bs2f(w2.y);
        float2 p6 = bs2f(w3.x), p7 = bs2f(w3.y);
        ax += p0.y * __builtin_amdgcn_rcpf(1.0f + __expf(-(k2.x + p0.x)));
        ay += p1.y * __builtin_amdgcn_rcpf(1.0f + __expf(-(k2.y + p1.x)));
        cx += p2.y * __builtin_amdgcn_rcpf(1.0f + __expf(-(k2.x + p2.x)));
        cy += p3.y * __builtin_amdgcn_rcpf(1.0f + __expf(-(k2.y + p3.x)));
        ax += p4.y * __builtin_amdgcn_rcpf(1.0f + __expf(-(k2.x + p4.x)));
        ay += p5.y * __builtin_amdgcn_rcpf(1.0f + __expf(-(k2.y + p5.x)));
        cx += p6.y * __builtin_amdgcn_rcpf(1.0f + __expf(-(k2.x + p6.x)));
        cy += p7.y * __builtin_amdgcn_rcpf(1.0f + __expf(-(k2.y + p7.x)));
    }
    for (; i < dg; ++i) {
        int s0 = sp[i];
        uint2 w0 = qvu[(size_t)s0 * 64 + lane];
        float2 p0 = bs2f(w0.x), p1 = bs2f(w0.y);
        ax += p0.y * __builtin_amdgcn_rcpf(1.0f + __expf(-(k2.x + p0.x)));
        ay += p1.y * __builtin_amdgcn_rcpf(1.0f + __expf(-(k2.y + p1.x)));
    }
    ax += cx; ay += cy;

    float2 sk = bs2f(skipu[(size_t)d * 64 + lane]);
    float2 hi = bs2f(hin1u[(size_t)d * 64 + lane]);
    float2 gv = *(const float2*)(g + lane * 2);
    float2 bt = *(const float2*)(beta + lane * 2);
    float ox = (hi.x + sk.x + ax) * (gv.x * rs) + bt.x;
    float oy = (hi.y + sk.y + ay) * (gv.y * rs) + bt.y;
    hlocal_u[(size_t)d * 64 + lane] = pk2(ox, oy);
}

// ---------------------------------------------------------------------------
// k5: MFMA flash attention. 256 blocks of 512 threads (8 waves, 64 q-rows
// each) -> 16 waves/CU (2x R12 occupancy). exp2-domain softmax (q pre-scaled
// by 1/sqrt(32)*log2(e) at in_proj); defer-max THR = 8*log2(e).
// ---------------------------------------------------------------------------
__device__ __forceinline__ void lswap(unsigned int& X, unsigned int& Y, bool hi) {
    unsigned int Xs = (unsigned int)__shfl_xor((int)X, 32);
    unsigned int Ys = (unsigned int)__shfl_xor((int)Y, 32);
    unsigned int Xn = hi ? Ys : X;
    unsigned int Yn = hi ? Y  : Xs;
    X = Xn; Y = Yn;
}

__global__ __launch_bounds__(512)
void attn_mfma(const short* __restrict__ qkv, short* __restrict__ ctx)
{
    __shared__ __align__(16) short ldsK[512 * 40];    // 40 KB, reused as O
    __shared__ __align__(16) short ldsVt[32 * 512];   // 32 KB, swizzled

    const int blk  = blockIdx.x;         // B*H = 256
    const int h    = blk & 3;
    const int b    = blk >> 2;
    const int tid  = threadIdx.x;        // 0..511
    const int lane = tid & 63;
    const int wid  = tid >> 6;           // 0..7
    const int lq = lane & 31;
    const int lg = lane >> 5;
    const size_t gbase = (size_t)(b * 512) * 384 + h * 32;

    // stage K rows (512 keys x 32 d, row stride 40 shorts)
    #pragma unroll
    for (int i = 0; i < 4; ++i) {
        int c = tid + i * 512;              // 0..2047
        int key = c >> 2, part = c & 3;
        bf8 v = *(const bf8*)(qkv + gbase + (size_t)key * 384 + 128 + part * 8);
        *(bf8*)(ldsK + key * 40 + part * 8) = v;
    }
    // stage V^T (rows d=0..31, 1024 B each, swizzled)
    if (tid < 256) {
        int p = tid;                        // key pair (2p, 2p+1)
        const short* v0 = qkv + gbase + (size_t)(2 * p) * 384 + 256;
        const short* v1 = v0 + 384;
        bf8 r0[4], r1[4];
        #pragma unroll
        for (int i = 0; i < 4; ++i) { r0[i] = *(const bf8*)(v0 + i * 8);
                                      r1[i] = *(const bf8*)(v1 + i * 8); }
        #pragma unroll
        for (int d = 0; d < 32; ++d) {
            unsigned int w = ((unsigned int)(unsigned short)r0[d >> 3][d & 7]) |
                             (((unsigned int)(unsigned short)r1[d >> 3][d & 7]) << 16);
            *(unsigned int*)((char*)ldsVt + d * 1024 + ((4 * p) ^ ((d & 7) << 4))) = w;
        }
    }
    const int qoff = wid * 64;
    bf8 qf[2][2];
    #pragma unroll
    for (int qg = 0; qg < 2; ++qg)
        #pragma unroll
        for (int kh = 0; kh < 2; ++kh)
            qf[qg][kh] = *(const bf8*)(qkv + gbase +
                           (size_t)(qoff + qg * 32 + lq) * 384 + kh * 16 + lg * 8);
    __syncthreads();

    const f32x16 Z16 = {0.f,0.f,0.f,0.f,0.f,0.f,0.f,0.f,0.f,0.f,0.f,0.f,0.f,0.f,0.f,0.f};
    f32x16 o[2] = {Z16, Z16};
    float mreg[2] = {-1e30f, -1e30f};
    float lreg[2] = {0.f, 0.f};
    const bool hiw = (lg != 0);

    for (int kt = 0; kt < 16; ++kt) {
        bf8 ak[2], vt[2];
        #pragma unroll
        for (int kh = 0; kh < 2; ++kh) {
            ak[kh] = *(const bf8*)(ldsK + (kt * 32 + lq) * 40 + kh * 16 + lg * 8);
            int kbyte = (kt * 32 + kh * 16 + lg * 8) * 2;
            vt[kh] = *(const bf8*)((const char*)ldsVt + lq * 1024 +
                                   (kbyte ^ ((lq & 7) << 4)));
        }
        #pragma unroll
        for (int qg = 0; qg < 2; ++qg) {
            f32x16 s = Z16;
            s = __builtin_amdgcn_mfma_f32_32x32x16_bf16(ak[0], qf[qg][0], s, 0, 0, 0);
            s = __builtin_amdgcn_mfma_f32_32x32x16_bf16(ak[1], qf[qg][1], s, 0, 0, 0);
            float t0 = fmaxf(fmaxf(s[0],  s[1]),  s[2]);
            float t1 = fmaxf(fmaxf(s[3],  s[4]),  s[5]);
            float t2 = fmaxf(fmaxf(s[6],  s[7]),  s[8]);
            float t3 = fmaxf(fmaxf(s[9],  s[10]), s[11]);
            float t4 = fmaxf(fmaxf(s[12], s[13]), s[14]);
            float mt = fmaxf(fmaxf(fmaxf(t0, t1), t2), fmaxf(fmaxf(t3, t4), s[15]));
            mt = fmaxf(mt, __shfl_xor(mt, 32));
            if (__any(mt > mreg[qg] + 11.5415603f)) {    // defer-max, log2 domain
                float mnew = fmaxf(mreg[qg], mt);
                float corr = exp2f(mreg[qg] - mnew);
                mreg[qg] = mnew;
                lreg[qg] *= corr;
                #pragma unroll
                for (int r = 0; r < 16; ++r) o[qg][r] *= corr;
            }
            float m = mreg[qg];
            float p[16]; float ps = 0.f;
            #pragma unroll
            for (int r = 0; r < 16; ++r) { p[r] = exp2f(s[r] - m); ps += p[r]; }
            ps += __shfl_xor(ps, 32);
            lreg[qg] += ps;
            unsigned int w0 = pk2(p[0],  p[1]),  w1 = pk2(p[2],  p[3]);
            unsigned int w2 = pk2(p[4],  p[5]),  w3 = pk2(p[6],  p[7]);
            unsigned int w4 = pk2(p[8],  p[9]),  w5 = pk2(p[10], p[11]);
            unsigned int w6 = pk2(p[12], p[13]), w7 = pk2(p[14], p[15]);
            lswap(w0, w2, hiw); lswap(w1, w3, hiw);
            lswap(w4, w6, hiw); lswap(w5, w7, hiw);
            union { unsigned int u[4]; bf8 v; } P0, P1;
            P0.u[0] = w0; P0.u[1] = w1; P0.u[2] = w2; P0.u[3] = w3;
            P1.u[0] = w4; P1.u[1] = w5; P1.u[2] = w6; P1.u[3] = w7;
            o[qg] = __builtin_amdgcn_mfma_f32_32x32x16_bf16(vt[0], P0.v, o[qg], 0, 0, 0);
            o[qg] = __builtin_amdgcn_mfma_f32_32x32x16_bf16(vt[1], P1.v, o[qg], 0, 0, 0);
        }
    }

    __syncthreads();
    short* ldsO = ldsK;                    // [512 q][32 d], byte ^ ((q&7)<<3) : 32 KB
    #pragma unroll
    for (int qg = 0; qg < 2; ++qg) {
        float inv = 1.0f / lreg[qg];
        int ql = qoff + qg * 32 + lq;      // 0..511
        #pragma unroll
        for (int b4 = 0; b4 < 4; ++b4) {
            short4 pkv;
            pkv.x = f2bs(o[qg][b4 * 4 + 0] * inv);
            pkv.y = f2bs(o[qg][b4 * 4 + 1] * inv);
            pkv.z = f2bs(o[qg][b4 * 4 + 2] * inv);
            pkv.w = f2bs(o[qg][b4 * 4 + 3] * inv);
            int dbyte = (8 * b4 + 4 * lg) * 2;
            *(short4*)((char*)ldsO + ql * 64 + (dbyte ^ ((ql & 7) << 3))) = pkv;
        }
    }
    __syncthreads();
    {
        int ql = tid;                       // 0..511
        short* dst = ctx + (size_t)(b * 512 + ql) * 128 + h * 32;
        #pragma unroll
        for (int i = 0; i < 8; ++i) {
            short4 part = *(short4*)((char*)ldsO + ql * 64 + ((i * 8) ^ ((ql & 7) << 3)));
            *(short4*)(dst + i * 4) = part;
        }
    }
}

// ---------------------------------------------------------------------------
// k6: FUSED out_proj+combine+FFN+finalBN (R11-proven). 512 blocks.
// ---------------------------------------------------------------------------
__global__ __launch_bounds__(256)
void outproj_ff_kernel(const short* __restrict__ ctxb, const short* __restrict__ wbf,
                       const float* __restrict__ bout,
                       const short* __restrict__ hin1b, const short* __restrict__ hlocb,
                       const float* __restrict__ g1a, const float* __restrict__ b1a,
                       const float* __restrict__ b1, const float* __restrict__ b2,
                       const float* __restrict__ g2, const float* __restrict__ b2g,
                       float* __restrict__ out)
{
    __shared__ __align__(16) short ldsH[64 * 128];   // 16 KB, byte ^ ((row&7)<<4)
    __shared__ __align__(16) short ldsF[64 * 256];   // 32 KB, byte ^ ((row&7)<<4)
    const int my = blockIdx.x;
    const int lane = threadIdx.x & 63;
    const int wid  = threadIdx.x >> 6;
    const int lrow = lane & 15;
    const int lk   = (lane >> 4) * 8;
    const int rbase = (lane >> 4) * 4;
    const float rs = 0.9999950000374998f;

    // ---- phase 0: out_proj + combine -> ldsH ----
    {
        const int m0 = (wid >> 1) * 32;              // local row base (0/32)
        const int n0 = (wid & 1) * 64;
        f32x4 acc[2][4] = {};
        const short* Ap = ctxb + (size_t)(my * 64 + m0 + lrow) * 128 + lk;
        const short* Wp = wbf + 131072 + (size_t)(n0 + lrow) * 128 + lk;
        #pragma unroll
        for (int ks = 0; ks < 128; ks += 32) {
            bf8 af[2], wf[4];
            af[0] = *(const bf8*)(Ap + ks);
            af[1] = *(const bf8*)(Ap + 16 * 128 + ks);
            #pragma unroll
            for (int j = 0; j < 4; ++j) wf[j] = *(const bf8*)(Wp + (size_t)j * 16 * 128 + ks);
            #pragma unroll
            for (int i = 0; i < 2; ++i)
                #pragma unroll
                for (int j = 0; j < 4; ++j)
                    acc[i][j] = __builtin_amdgcn_mfma_f32_16x16x32_bf16(af[i], wf[j], acc[i][j], 0, 0, 0);
        }
        #pragma unroll
        for (int j = 0; j < 4; ++j) {
            int col = n0 + j * 16 + lrow;            // 0..127
            float bcol = bout[col];
            float gsc = g1a[col] * rs;
            float bsc = b1a[col];
            #pragma unroll
            for (int i = 0; i < 2; ++i)
                #pragma unroll
                for (int r = 0; r < 4; ++r) {
                    int rl = m0 + i * 16 + rbase + r;     // 0..63 local
                    size_t idx = (size_t)(my * 64 + rl) * 128 + col;
                    float v = acc[i][j][r] + bcol;
                    float o = bs1f(hlocb[idx]) + (bs1f(hin1b[idx]) + v) * gsc + bsc;
                    int byte = (rl * 256 + col * 2) ^ ((rl & 7) << 4);
                    *(short*)((char*)ldsH + byte) = f2bs(o);
                }
        }
    }
    __syncthreads();
    // ---- phase 1: ff1 -> ldsF ----
    {
        const int m0 = (wid >> 1) * 32;
        const int n0 = (wid & 1) * 128;
        f32x4 acc[2][8] = {};
        const short* Wp = wbf + 147456 + (size_t)(n0 + lrow) * 128 + lk;
        #pragma unroll
        for (int ks = 0; ks < 128; ks += 32) {
            bf8 af[2], wf[8];
            #pragma unroll
            for (int i = 0; i < 2; ++i) {
                int row = m0 + lrow + i * 16;
                int byte = (row * 256 + (ks + lk) * 2) ^ ((row & 7) << 4);
                af[i] = *(const bf8*)((const char*)ldsH + byte);
            }
            #pragma unroll
            for (int j = 0; j < 8; ++j) wf[j] = *(const bf8*)(Wp + (size_t)j * 16 * 128 + ks);
            #pragma unroll
            for (int i = 0; i < 2; ++i)
                #pragma unroll
                for (int j = 0; j < 8; ++j)
                    acc[i][j] = __builtin_amdgcn_mfma_f32_16x16x32_bf16(af[i], wf[j], acc[i][j], 0, 0, 0);
        }
        #pragma unroll
        for (int j = 0; j < 8; ++j) {
            int col = n0 + j * 16 + lrow;            // 0..255
            float bc = b1[col];
            #pragma unroll
            for (int i = 0; i < 2; ++i)
                #pragma unroll
                for (int r = 0; r < 4; ++r) {
                    int rl = m0 + i * 16 + rbase + r;    // 0..63
                    float v = fmaxf(acc[i][j][r] + bc, 0.f);
                    int byte = (rl * 512 + col * 2) ^ ((rl & 7) << 4);
                    *(short*)((char*)ldsF + byte) = f2bs(v);
                }
        }
    }
    __syncthreads();
    // ---- phase 2: ff2 + final BN (residual from ldsH) ----
    {
        const int m0 = (wid >> 1) * 32;
        const int n0 = (wid & 1) * 64;
        f32x4 acc[2][4] = {};
        const short* Wp = wbf + 180224 + (size_t)(n0 + lrow) * 256 + lk;
        #pragma unroll
        for (int ks = 0; ks < 256; ks += 32) {
            bf8 af[2], wf[4];
            #pragma unroll
            for (int i = 0; i < 2; ++i) {
                int row = m0 + lrow + i * 16;
                int byte = (row * 512 + (ks + lk) * 2) ^ ((row & 7) << 4);
                af[i] = *(const bf8*)((const char*)ldsF + byte);
            }
            #pragma unroll
            for (int j = 0; j < 4; ++j) wf[j] = *(const bf8*)(Wp + (size_t)j * 16 * 256 + ks);
            #pragma unroll
            for (int i = 0; i < 2; ++i)
                #pragma unroll
                for (int j = 0; j < 4; ++j)
                    acc[i][j] = __builtin_amdgcn_mfma_f32_16x16x32_bf16(af[i], wf[j], acc[i][j], 0, 0, 0);
        }
        #pragma unroll
        for (int j = 0; j < 4; ++j) {
            int col = n0 + j * 16 + lrow;
            float bc = b2[col];
            float gsc = g2[col] * rs;
            float bsc = b2g[col];
            #pragma unroll
            for (int i = 0; i < 2; ++i)
                #pragma unroll
                for (int r = 0; r < 4; ++r) {
                    int rl = m0 + i * 16 + rbase + r;
                    int hbyte = (rl * 256 + col * 2) ^ ((rl & 7) << 4);
                    float hres = bs1f(*(const short*)((const char*)ldsH + hbyte));
                    float v = acc[i][j][r] + bc;
                    out[(size_t)(my * 64 + rl) * 128 + col] = (hres + v) * gsc + bsc;
                }
        }
    }
}

// ---------------------------------------------------------------------------
extern "C" void kernel_launch(void* const* d_in, const int* in_sizes, int n_in,
                              void* d_out, int out_size, void* d_ws, size_t ws_size,
                              hipStream_t stream)
{
    (void)in_sizes; (void)n_in; (void)out_size; (void)ws_size;

    const float* x    = (const float*)d_in[0];
    const int*   ei   = (const int*)d_in[1];
    const float* Wres = (const float*)d_in[3];
    const float* bres = (const float*)d_in[4];
    const float* Wk   = (const float*)d_in[5];
    const float* bk   = (const float*)d_in[6];
    const float* Wq   = (const float*)d_in[7];
    const float* bq   = (const float*)d_in[8];
    const float* Wv   = (const float*)d_in[9];
    const float* bv   = (const float*)d_in[10];
    const float* Wsk  = (const float*)d_in[11];
    const float* bsk  = (const float*)d_in[12];
    const float* g1l  = (const float*)d_in[13];
    const float* b1l  = (const float*)d_in[14];
    const float* g1a  = (const float*)d_in[15];
    const float* b1a  = (const float*)d_in[16];
    const float* Win  = (const float*)d_in[17];
    const float* bin  = (const float*)d_in[18];
    const float* Wout = (const float*)d_in[19];
    const float* bout = (const float*)d_in[20];
    const float* W1   = (const float*)d_in[21];
    const float* b1   = (const float*)d_in[22];
    const float* W2   = (const float*)d_in[23];
    const float* b2   = (const float*)d_in[24];
    const float* g2   = (const float*)d_in[25];
    const float* b2g  = (const float*)d_in[26];
    float* out = (float*)d_out;

    float* ws = (float*)d_ws;
    // ----- workspace layout (float-slot offsets), lifetimes k1..k6 -----
    short* hin1b = (short*)ws;                        // [0,0.5NM)  w:k2 r:k3,k4,k6
    short* kbv   = (short*)(ws + NM / 2);             // [0.5NM,NM) w:k2 r:k4
    short* qvb   = (short*)(ws + NM);                 // [NM,2NM)   w:k2 r:k4 (q,v ilv)
    short* skipb = (short*)(ws + 2 * NM);             // [2NM,2.5NM) w:k2 r:k4
    short* xb    = (short*)(ws + 2 * NM + NM / 2);    // [2.5NM,3NM) w:k1 r:k2
    short* qkvb  = (short*)(ws + 3 * NM);             // [3NM,4.5NM) w:k3 r:k5
    short* hlocb = (short*)(ws + 4 * NM + NM / 2);    // [4.5NM,5NM) w:k4 r:k6
    // slot ints/ushorts overlay [5NM, ...) — dead after k4; ctxb (w:k5) reuses it
    int* deg = (int*)(ws + 5 * NM);                   // [N] w:memset, rmw:k1 r:k4
    unsigned short* slots = (unsigned short*)(deg + N_NODES);  // [N*CAP] w:k1 r:k4
    short* ctxb  = (short*)(ws + 5 * NM);             // [5NM,5.5NM) w:k5 r:k6
    short* wbf   = (short*)(ws + 6 * NM);             // 212992 shorts = 106496 fslots
    float* bcat  = ws + 6 * NM + 106496;              // [640] f32
    // total extent: 6NM + 107136 floats ≈ 101.1 MB

    dim3 blk(256);
    // 1/sqrt(32) * log2(e)  (exp2-domain softmax)
    const float qscale = 0.17677669529663687f * 1.4426950408889634f;

    // 0. zero deg
    hipMemsetAsync((void*)deg, 0, N_NODES * sizeof(int), stream);

    // 1. scatter (first) + cvt
    cvt_scatter_kernel<<<dim3(6353), blk, 0, stream>>>(
        x, Wres, Wk, Wq, Wv, Wsk, Win, Wout, W1, W2,
        bres, bk, bq, bv, bsk, ei, xb, wbf, bcat, deg, slots);

    // 2. proj5 GEMM (clean)
    proj5_kernel<<<dim3(2560), blk, 0, stream>>>(
        xb, wbf, bcat, hin1b, kbv, qvb, skipb);

    // 3. in_proj GEMM (clean)
    inproj_kernel<<<dim3(1536), blk, 0, stream>>>(
        hin1b, wbf, bin, qkvb, qscale);

    // 4. gather + skip + BN (slot lists)
    gather_local_kernel<<<dim3(N_NODES / 4), blk, 0, stream>>>(
        (const unsigned int*)kbv, (const uint2*)qvb, (const unsigned int*)skipb,
        (const unsigned int*)hin1b, deg, slots, g1l, b1l,
        (unsigned int*)hlocb);

    // 5. attention (512-thread blocks, 2x occupancy, exp2 softmax)
    attn_mfma<<<dim3(256), dim3(512), 0, stream>>>(qkvb, ctxb);

    // 6. fused out_proj + combine + FFN + final BN
    outproj_ff_kernel<<<dim3(512), blk, 0, stream>>>(
        ctxb, wbf, bout, hin1b, hlocb, g1a, b1a, b1, b2, g2, b2g, out);
}